// Round 4
// baseline (7857.959 us; speedup 1.0000x reference)
//
#include <hip/hip_runtime.h>
#include <hip/hip_bf16.h>
#include <math.h>

// ---------------------------------------------------------------------------
// Dims (fixed by the reference)
// ---------------------------------------------------------------------------
#define BB    1024      // batch
#define NCAND 100000    // candidates
#define DD    256       // d_main
#define CC    96        // context size
#define HH    8         // heads
#define DH    32        // head dim
#define NBLK  2
#define DENC  512
#define DFF   1024
#define NNUM  64
#define NCLS  10
#define CHQ   256       // query chunk for sims buffer

// top-k select: fixed-point buckets over sims in [-1,1]
#define NBUCK  4096
#define BSCALE 2048.0f
#define TIECAP 8192

// ---------------------------------------------------------------------------
// Generic fp32 tiled GEMM: C[M,N] = act(A[M,K] @ B + bias) [+ res]
// TB: B is N-major (N x K, take dot of rows)  else K x N row-major.
// ---------------------------------------------------------------------------
#define BM 64
#define BN 64
#define BK 16

template <bool TB, bool RELU, bool RES>
__global__ __launch_bounds__(256) void gemm_k(const float* __restrict__ A,
                                              const float* __restrict__ B,
                                              const float* __restrict__ bias,
                                              const float* __restrict__ res,
                                              float* __restrict__ C,
                                              int M, int N, int K) {
    __shared__ __align__(16) float As[BK][BM + 4];
    __shared__ __align__(16) float Bs[BK][BN + 4];
    const int tid = threadIdx.x;
    const int bm = blockIdx.y * BM;
    const int bn = blockIdx.x * BN;
    const int tm = (tid >> 4) << 2;   // 0..60
    const int tn = (tid & 15) << 2;   // 0..60

    float acc[4][4] = {};

    for (int k0 = 0; k0 < K; k0 += BK) {
#pragma unroll
        for (int l = 0; l < 4; ++l) {
            int lin = l * 256 + tid;
            int m = lin >> 4;
            int k = lin & 15;
            As[k][m] = A[(size_t)(bm + m) * K + k0 + k];
        }
#pragma unroll
        for (int l = 0; l < 4; ++l) {
            int lin = l * 256 + tid;
            if (TB) {
                int n = lin >> 4;
                int k = lin & 15;
                int gn = bn + n;
                Bs[k][n] = (gn < N) ? B[(size_t)gn * K + k0 + k] : 0.f;
            } else {
                int k = lin >> 6;
                int n = lin & 63;
                int gn = bn + n;
                Bs[k][n] = (gn < N) ? B[(size_t)(k0 + k) * N + gn] : 0.f;
            }
        }
        __syncthreads();
#pragma unroll
        for (int k = 0; k < BK; ++k) {
            float4 a4 = *(const float4*)&As[k][tm];
            float4 b4 = *(const float4*)&Bs[k][tn];
            float av[4] = {a4.x, a4.y, a4.z, a4.w};
            float bv[4] = {b4.x, b4.y, b4.z, b4.w};
#pragma unroll
            for (int i = 0; i < 4; ++i)
#pragma unroll
                for (int j = 0; j < 4; ++j) acc[i][j] += av[i] * bv[j];
        }
        __syncthreads();
    }

#pragma unroll
    for (int i = 0; i < 4; ++i) {
        int r = bm + tm + i;
#pragma unroll
        for (int j = 0; j < 4; ++j) {
            int c = bn + tn + j;
            if (c < N) {
                float v = acc[i][j];
                if (bias) v += bias[c];
                if (RELU) v = fmaxf(v, 0.f);
                if (RES) v += res[(size_t)r * N + c];
                C[(size_t)r * N + c] = v;
            }
        }
    }
}

// ---------------------------------------------------------------------------
// LayerNorm over D=256 (one block per row)
// ---------------------------------------------------------------------------
__global__ __launch_bounds__(256) void ln_k(const float* __restrict__ x,
                                            const float* __restrict__ s,
                                            const float* __restrict__ b,
                                            float* __restrict__ o) {
    __shared__ float red[256];
    const int row = blockIdx.x, tid = threadIdx.x;
    float v = x[(size_t)row * DD + tid];
    red[tid] = v;
    __syncthreads();
    for (int st = 128; st > 0; st >>= 1) {
        if (tid < st) red[tid] += red[tid + st];
        __syncthreads();
    }
    float mean = red[0] * (1.f / DD);
    __syncthreads();
    float d = v - mean;
    red[tid] = d * d;
    __syncthreads();
    for (int st = 128; st > 0; st >>= 1) {
        if (tid < st) red[tid] += red[tid + st];
        __syncthreads();
    }
    float var = red[0] * (1.f / DD);
    o[(size_t)row * DD + tid] = d / sqrtf(var + 1e-5f) * s[tid] + b[tid];
}

// ---------------------------------------------------------------------------
// Row L2-normalize (D=256)
// ---------------------------------------------------------------------------
__global__ __launch_bounds__(256) void l2norm_k(const float* __restrict__ in,
                                                float* __restrict__ out) {
    __shared__ float red[256];
    const int row = blockIdx.x, tid = threadIdx.x;
    float v = in[(size_t)row * DD + tid];
    red[tid] = v * v;
    __syncthreads();
    for (int st = 128; st > 0; st >>= 1) {
        if (tid < st) red[tid] += red[tid + st];
        __syncthreads();
    }
    float inv = 1.f / sqrtf(red[0]);
    out[(size_t)row * DD + tid] = v * inv;
}

// ---------------------------------------------------------------------------
// Top-96 pipeline over a sims chunk [CHQ rows x NCAND].
// Bucket index is monotone in sim value; equal values -> equal bucket, so
// {bucket > B1} + exact fp32 select inside bucket B1 == exact fp32 top-96 set.
// ---------------------------------------------------------------------------
__device__ inline int bucket_of(float s) {
    int b = (int)((s + 1.0f) * BSCALE);
    return b < 0 ? 0 : (b > NBUCK - 1 ? NBUCK - 1 : b);
}

// grid (25, CHQ); each block handles 1000 float4 of one query row
__global__ __launch_bounds__(256) void hist_k(const float* __restrict__ sims,
                                              unsigned* __restrict__ ghist) {
    const int q = blockIdx.y, tid = threadIdx.x;
    const float4* r4 = (const float4*)(sims + (size_t)q * NCAND);
    unsigned* h = ghist + (size_t)q * NBUCK;
    const int base4 = blockIdx.x * 1000;
    for (int t = tid; t < 1000; t += 256) {
        float4 v = r4[base4 + t];
        atomicAdd(&h[bucket_of(v.x)], 1u);
        atomicAdd(&h[bucket_of(v.y)], 1u);
        atomicAdd(&h[bucket_of(v.z)], 1u);
        atomicAdd(&h[bucket_of(v.w)], 1u);
    }
}

// one block per query: find boundary bucket B1 (cum from top reaches >= 96)
__global__ __launch_bounds__(256) void thr_k(const unsigned* __restrict__ ghist,
                                             int* __restrict__ B1v,
                                             unsigned* __restrict__ cnt_def,
                                             unsigned* __restrict__ cnt_tie) {
    __shared__ unsigned part[256];
    const int q = blockIdx.x, tid = threadIdx.x;
    const unsigned* h = ghist + (size_t)q * NBUCK;
    unsigned s = 0;
#pragma unroll
    for (int i = 0; i < 16; ++i) s += h[tid * 16 + i];
    part[tid] = s;
    __syncthreads();
    if (tid == 0) {
        unsigned cum = 0;
        int seg = 0;
        for (int t = 255; t >= 0; --t) {
            if (cum + part[t] >= CC) { seg = t; break; }
            cum += part[t];
        }
        int b1 = seg * 16;
        for (int b = seg * 16 + 15; b >= seg * 16; --b) {
            if (cum + h[b] >= CC) { b1 = b; break; }
            cum += h[b];
        }
        B1v[q] = b1;
        cnt_def[q] = 0;
        cnt_tie[q] = 0;
    }
}

// grid (25, CHQ): emit definite winners (bucket > B1, count < 96 guaranteed)
// directly into the output slots; boundary-bucket ties into tie buffers.
__global__ __launch_bounds__(256) void compact_k(const float* __restrict__ sims,
                                                 const int* __restrict__ B1v,
                                                 unsigned* __restrict__ cnt_def,
                                                 unsigned* __restrict__ cnt_tie,
                                                 float* __restrict__ tieval,
                                                 int* __restrict__ tieidx,
                                                 int* __restrict__ idxout, int qo) {
    const int q = blockIdx.y, tid = threadIdx.x;
    const float4* r4 = (const float4*)(sims + (size_t)q * NCAND);
    const int b1 = B1v[q];
    int* myout = idxout + (size_t)(qo + q) * CC;
    float* tv = tieval + (size_t)q * TIECAP;
    int* tix = tieidx + (size_t)q * TIECAP;
    const int base4 = blockIdx.x * 1000;
    for (int t = tid; t < 1000; t += 256) {
        float4 v = r4[base4 + t];
        float vv[4] = {v.x, v.y, v.z, v.w};
        int j = (base4 + t) * 4;
#pragma unroll
        for (int u = 0; u < 4; ++u) {
            int b = bucket_of(vv[u]);
            if (b > b1) {
                unsigned p = atomicAdd(&cnt_def[q], 1u);
                myout[p] = j + u;
            } else if (b == b1) {
                unsigned p = atomicAdd(&cnt_tie[q], 1u);
                if (p < TIECAP) { tv[p] = vv[u]; tix[p] = j + u; }
            }
        }
    }
}

// one block per query: exact fp32 selection of remaining slots among ties
__global__ __launch_bounds__(256) void final_k(const unsigned* __restrict__ cnt_def,
                                               const unsigned* __restrict__ cnt_tie,
                                               float* __restrict__ tieval,
                                               const int* __restrict__ tieidx,
                                               int* __restrict__ idxout, int qo) {
    __shared__ float rv[256];
    __shared__ int rj[256];
    const int q = blockIdx.x, tid = threadIdx.x;
    const int base = (int)cnt_def[q];
    const int rem = CC - base;
    unsigned ct = cnt_tie[q];
    const int nt = (int)(ct < (unsigned)TIECAP ? ct : (unsigned)TIECAP);
    float* tv = tieval + (size_t)q * TIECAP;
    const int* tix = tieidx + (size_t)q * TIECAP;
    int* myout = idxout + (size_t)(qo + q) * CC;
    for (int r = 0; r < rem; ++r) {
        float bvv = -1e30f;
        int bj = -1;
        for (int t = tid; t < nt; t += 256)
            if (tv[t] > bvv) { bvv = tv[t]; bj = t; }
        rv[tid] = bvv;
        rj[tid] = bj;
        __syncthreads();
        for (int st = 128; st > 0; st >>= 1) {
            if (tid < st && rv[tid + st] > rv[tid]) { rv[tid] = rv[tid + st]; rj[tid] = rj[tid + st]; }
            __syncthreads();
        }
        if (tid == 0) {
            myout[base + r] = tix[rj[0]];
            tv[rj[0]] = -1e30f;
        }
        __syncthreads();
    }
}

// ---------------------------------------------------------------------------
// ctx[b,c,:] = candidate_k[idx[b,c],:] + label_emb[candidate_y[idx[b,c]],:]
// ---------------------------------------------------------------------------
__global__ __launch_bounds__(256) void ctx_k(const int* __restrict__ idx,
                                             const float* __restrict__ ck,
                                             const int* __restrict__ cy,
                                             const float* __restrict__ le,
                                             float* __restrict__ ctx) {
    const int row = blockIdx.x, tid = threadIdx.x;
    const int i = idx[row];
    const int y = cy[i];
    ctx[(size_t)row * DD + tid] = ck[(size_t)i * DD + tid] + le[(size_t)y * DD + tid];
}

// ---------------------------------------------------------------------------
// Wf[(h*256+e), f] = sum_d wv[e, h*32+d] * wo[h*32+d, f]
// ---------------------------------------------------------------------------
__global__ __launch_bounds__(256) void wfuse_k(const float* __restrict__ wv,
                                               const float* __restrict__ wo,
                                               float* __restrict__ Wf) {
    const int r = blockIdx.x;          // h*256 + e
    const int h = r >> 8, e = r & 255;
    const int f = threadIdx.x;
    float acc = 0.f;
#pragma unroll
    for (int d = 0; d < DH; ++d)
        acc += wv[(size_t)e * DD + h * DH + d] * wo[(size_t)(h * DH + d) * DD + f];
    Wf[(size_t)r * DD + f] = acc;
}

// c0[f] = bv @ wo + bo
__global__ __launch_bounds__(256) void c0_k(const float* __restrict__ bv,
                                            const float* __restrict__ wo,
                                            const float* __restrict__ bo,
                                            float* __restrict__ c0) {
    const int f = threadIdx.x;
    float acc = bo[f];
    for (int r = 0; r < DD; ++r) acc += bv[r] * wo[(size_t)r * DD + f];
    c0[f] = acc;
}

// ---------------------------------------------------------------------------
// Fused attention (per batch row b)
// ---------------------------------------------------------------------------
__global__ __launch_bounds__(256) void attn_k(const float* __restrict__ qb,
                                              const float* __restrict__ wk,
                                              const float* __restrict__ ctx,
                                              float* __restrict__ mout) {
    __shared__ float qs[DD];
    __shared__ float ts[HH * DD];
    __shared__ float ss[HH * CC];
    const int b = blockIdx.x, tid = threadIdx.x;
    qs[tid] = qb[(size_t)b * DD + tid];
    __syncthreads();

    for (int idx = tid; idx < HH * DD; idx += 256) {
        const int h = idx >> 8, e = idx & 255;
        float acc = 0.f;
#pragma unroll
        for (int d = 0; d < DH; ++d) acc += qs[h * DH + d] * wk[(size_t)e * DD + h * DH + d];
        ts[idx] = acc;
    }
    __syncthreads();

    const float scale = 0.17677669529663687f;  // 1/sqrt(32)
    const float* cb = ctx + (size_t)b * CC * DD;
    for (int o = tid; o < HH * CC; o += 256) {
        const int c = o >> 3, h = o & 7;
        const float* cr = cb + (size_t)c * DD;
        const float* th = ts + h * DD;
        float acc = 0.f;
        for (int e = 0; e < DD; ++e) acc += cr[e] * th[e];
        ss[h * CC + c] = acc * scale;
    }
    __syncthreads();

    if (tid < HH) {
        const int h = tid;
        float mx = -1e30f;
        for (int c = 0; c < CC; ++c) mx = fmaxf(mx, ss[h * CC + c]);
        float sum = 0.f;
        for (int c = 0; c < CC; ++c) {
            float e = expf(ss[h * CC + c] - mx);
            ss[h * CC + c] = e;
            sum += e;
        }
        float inv = 1.f / sum;
        for (int c = 0; c < CC; ++c) ss[h * CC + c] *= inv;
    }
    __syncthreads();

    float acc[HH] = {};
    for (int c = 0; c < CC; ++c) {
        float v = cb[(size_t)c * DD + tid];
#pragma unroll
        for (int h = 0; h < HH; ++h) acc[h] += ss[h * CC + c] * v;
    }
#pragma unroll
    for (int h = 0; h < HH; ++h) mout[(size_t)b * (HH * DD) + h * DD + tid] = acc[h];
}

// ---------------------------------------------------------------------------
// Host launcher
// ---------------------------------------------------------------------------
extern "C" void kernel_launch(void* const* d_in, const int* in_sizes, int n_in,
                              void* d_out, int out_size, void* d_ws, size_t ws_size,
                              hipStream_t stream) {
    (void)in_sizes; (void)n_in; (void)out_size; (void)ws_size;
    const float* x_num  = (const float*)d_in[0];
    const float* cand_k = (const float*)d_in[1];
    const int*   cand_y = (const int*)d_in[2];
    const float* enc_w0 = (const float*)d_in[3];
    const float* enc_b0 = (const float*)d_in[4];
    const float* enc_ln_s = (const float*)d_in[5];
    const float* enc_ln_b = (const float*)d_in[6];
    const float* enc_w1 = (const float*)d_in[7];
    const float* enc_b1 = (const float*)d_in[8];
    const float* enc_w2 = (const float*)d_in[9];
    const float* enc_b2 = (const float*)d_in[10];
    const float* label_emb = (const float*)d_in[11];
    const float* ln1_s = (const float*)d_in[12];
    const float* ln1_b = (const float*)d_in[13];
    const float* wq = (const float*)d_in[14];
    const float* bq = (const float*)d_in[15];
    const float* wk = (const float*)d_in[16];
    // d_in[17] = bk : constant shift per (b,h) inside softmax -> drops out
    const float* wv = (const float*)d_in[18];
    const float* bv = (const float*)d_in[19];
    const float* wo = (const float*)d_in[20];
    const float* bo = (const float*)d_in[21];
    const float* ln2_s = (const float*)d_in[22];
    const float* ln2_b = (const float*)d_in[23];
    const float* fw1 = (const float*)d_in[24];
    const float* fb1 = (const float*)d_in[25];
    const float* fw2 = (const float*)d_in[26];
    const float* fb2 = (const float*)d_in[27];
    const float* head_w = (const float*)d_in[28];
    const float* head_b = (const float*)d_in[29];
    float* out = (float*)d_out;

    char* ws = (char*)d_ws;
    size_t off = 0;
    auto alloc = [&](size_t bytes) -> void* {
        void* p = ws + off;
        off += (bytes + 255) & ~(size_t)255;
        return p;
    };
    float* big  = (float*)alloc((size_t)CHQ * NCAND * 4);   // sims chunk, reused as ctx
    float* h0   = (float*)alloc((size_t)BB * DD * 4);
    float* h1   = (float*)alloc((size_t)BB * DENC * 4);
    float* hln  = (float*)alloc((size_t)BB * DD * 4);
    float* x    = (float*)alloc((size_t)BB * DD * 4);       // query, then residual stream
    float* qbuf = (float*)alloc((size_t)BB * DD * 4);
    int*   idxb = (int*)alloc((size_t)BB * CC * 4);
    float* mbuf = (float*)alloc((size_t)BB * HH * DD * 4);
    float* Wf   = (float*)alloc((size_t)HH * DD * DD * 4);
    float* c0   = (float*)alloc(DD * 4);
    float* ffh  = (float*)alloc((size_t)BB * DFF * 4);
    unsigned* ghist  = (unsigned*)alloc((size_t)CHQ * NBUCK * 4);
    int*      B1v    = (int*)alloc((size_t)CHQ * 4);
    unsigned* cntd   = (unsigned*)alloc((size_t)CHQ * 4);
    unsigned* cntt   = (unsigned*)alloc((size_t)CHQ * 4);
    float*    tieval = (float*)alloc((size_t)CHQ * TIECAP * 4);
    int*      tieidx = (int*)alloc((size_t)CHQ * TIECAP * 4);
    float* ctx  = big;

    dim3 blk(256);

    // ---- encoder ----
    gemm_k<false, false, false><<<dim3(DD / BN, BB / BM), blk, 0, stream>>>(
        x_num, enc_w0, enc_b0, nullptr, h0, BB, DD, NNUM);
    for (int i = 0; i < NBLK; ++i) {
        ln_k<<<BB, blk, 0, stream>>>(h0, enc_ln_s + i * DD, enc_ln_b + i * DD, hln);
        gemm_k<false, true, false><<<dim3(DENC / BN, BB / BM), blk, 0, stream>>>(
            hln, enc_w1 + (size_t)i * DD * DENC, enc_b1 + i * DENC, nullptr, h1, BB, DENC, DD);
        gemm_k<false, false, false><<<dim3(DD / BN, BB / BM), blk, 0, stream>>>(
            h1, enc_w2 + (size_t)i * DENC * DD, enc_b2 + i * DD, nullptr, h0, BB, DD, DENC);
    }
    l2norm_k<<<BB, blk, 0, stream>>>(h0, x);  // x = query

    // ---- retrieval: sims (fp32, chunked) + exact top-96 (bucket select) ----
    for (int ci = 0; ci < BB / CHQ; ++ci) {
        const int qo = ci * CHQ;
        hipMemsetAsync(ghist, 0, (size_t)CHQ * NBUCK * 4, stream);
        gemm_k<true, false, false><<<dim3((NCAND + BN - 1) / BN, CHQ / BM), blk, 0, stream>>>(
            x + (size_t)qo * DD, cand_k, nullptr, nullptr, big, CHQ, NCAND, DD);
        hist_k<<<dim3(25, CHQ), blk, 0, stream>>>(big, ghist);
        thr_k<<<CHQ, blk, 0, stream>>>(ghist, B1v, cntd, cntt);
        compact_k<<<dim3(25, CHQ), blk, 0, stream>>>(big, B1v, cntd, cntt, tieval, tieidx, idxb, qo);
        final_k<<<CHQ, blk, 0, stream>>>(cntd, cntt, tieval, tieidx, idxb, qo);
    }
    ctx_k<<<BB * CC, blk, 0, stream>>>(idxb, cand_k, cand_y, label_emb, ctx);

    // ---- transformer mixer (associativity-restructured attention) ----
    for (int i = 0; i < NBLK; ++i) {
        const size_t W = (size_t)i * DD * DD;
        ln_k<<<BB, blk, 0, stream>>>(x, ln1_s + i * DD, ln1_b + i * DD, hln);
        gemm_k<false, false, false><<<dim3(DD / BN, BB / BM), blk, 0, stream>>>(
            hln, wq + W, bq + i * DD, nullptr, qbuf, BB, DD, DD);
        wfuse_k<<<HH * DD, blk, 0, stream>>>(wv + W, wo + W, Wf);
        c0_k<<<1, blk, 0, stream>>>(bv + i * DD, wo + W, bo + i * DD, c0);
        attn_k<<<BB, blk, 0, stream>>>(qbuf, wk + W, ctx, mbuf);
        gemm_k<false, false, true><<<dim3(DD / BN, BB / BM), blk, 0, stream>>>(
            mbuf, Wf, c0, x, x, BB, DD, HH * DD);
        ln_k<<<BB, blk, 0, stream>>>(x, ln2_s + i * DD, ln2_b + i * DD, hln);
        gemm_k<false, true, false><<<dim3(DFF / BN, BB / BM), blk, 0, stream>>>(
            hln, fw1 + (size_t)i * DD * DFF, fb1 + i * DFF, nullptr, ffh, BB, DFF, DD);
        gemm_k<false, false, true><<<dim3(DD / BN, BB / BM), blk, 0, stream>>>(
            ffh, fw2 + (size_t)i * DFF * DD, fb2 + i * DD, x, x, BB, DD, DFF);
    }

    // ---- head ----
    gemm_k<false, false, false><<<dim3(1, BB / BM), blk, 0, stream>>>(
        x, head_w, head_b, nullptr, out, BB, NCLS, DD);
}

// Round 5
// 2654.294 us; speedup vs baseline: 2.9605x; 2.9605x over previous
//
#include <hip/hip_runtime.h>
#include <hip/hip_bf16.h>
#include <math.h>

// ---------------------------------------------------------------------------
// Dims (fixed by the reference)
// ---------------------------------------------------------------------------
#define BB    1024      // batch
#define NCAND 100000    // candidates
#define DD    256       // d_main
#define CC    96        // context size
#define HH    8         // heads
#define DH    32        // head dim
#define NBLK  2
#define DENC  512
#define DFF   1024
#define NNUM  64
#define NCLS  10
#define CHQ   256       // query chunk for sims buffer

// top-k select: fixed-point buckets over sims in [-1,1]
#define NBUCK  4096
#define BSCALE 2048.0f
#define TIECAP 8192
#define NSEG   8
#define SEG4   3125     // float4 per segment = NCAND/4/NSEG

// ---------------------------------------------------------------------------
// Generic fp32 tiled GEMM: C[M,N] = act(A[M,K] @ B + bias) [+ res]
// TB: B is N-major (N x K, take dot of rows)  else K x N row-major.
// ---------------------------------------------------------------------------
#define BM 64
#define BN 64
#define BK 16

template <bool TB, bool RELU, bool RES>
__global__ __launch_bounds__(256) void gemm_k(const float* __restrict__ A,
                                              const float* __restrict__ B,
                                              const float* __restrict__ bias,
                                              const float* __restrict__ res,
                                              float* __restrict__ C,
                                              int M, int N, int K) {
    __shared__ __align__(16) float As[BK][BM + 4];
    __shared__ __align__(16) float Bs[BK][BN + 4];
    const int tid = threadIdx.x;
    const int bm = blockIdx.y * BM;
    const int bn = blockIdx.x * BN;
    const int tm = (tid >> 4) << 2;   // 0..60
    const int tn = (tid & 15) << 2;   // 0..60

    float acc[4][4] = {};

    for (int k0 = 0; k0 < K; k0 += BK) {
#pragma unroll
        for (int l = 0; l < 4; ++l) {
            int lin = l * 256 + tid;
            int m = lin >> 4;
            int k = lin & 15;
            As[k][m] = A[(size_t)(bm + m) * K + k0 + k];
        }
#pragma unroll
        for (int l = 0; l < 4; ++l) {
            int lin = l * 256 + tid;
            if (TB) {
                int n = lin >> 4;
                int k = lin & 15;
                int gn = bn + n;
                Bs[k][n] = (gn < N) ? B[(size_t)gn * K + k0 + k] : 0.f;
            } else {
                int k = lin >> 6;
                int n = lin & 63;
                int gn = bn + n;
                Bs[k][n] = (gn < N) ? B[(size_t)(k0 + k) * N + gn] : 0.f;
            }
        }
        __syncthreads();
#pragma unroll
        for (int k = 0; k < BK; ++k) {
            float4 a4 = *(const float4*)&As[k][tm];
            float4 b4 = *(const float4*)&Bs[k][tn];
            float av[4] = {a4.x, a4.y, a4.z, a4.w};
            float bv[4] = {b4.x, b4.y, b4.z, b4.w};
#pragma unroll
            for (int i = 0; i < 4; ++i)
#pragma unroll
                for (int j = 0; j < 4; ++j) acc[i][j] += av[i] * bv[j];
        }
        __syncthreads();
    }

#pragma unroll
    for (int i = 0; i < 4; ++i) {
        int r = bm + tm + i;
#pragma unroll
        for (int j = 0; j < 4; ++j) {
            int c = bn + tn + j;
            if (c < N) {
                float v = acc[i][j];
                if (bias) v += bias[c];
                if (RELU) v = fmaxf(v, 0.f);
                if (RES) v += res[(size_t)r * N + c];
                C[(size_t)r * N + c] = v;
            }
        }
    }
}

// ---------------------------------------------------------------------------
// LayerNorm over D=256 (one block per row)
// ---------------------------------------------------------------------------
__global__ __launch_bounds__(256) void ln_k(const float* __restrict__ x,
                                            const float* __restrict__ s,
                                            const float* __restrict__ b,
                                            float* __restrict__ o) {
    __shared__ float red[256];
    const int row = blockIdx.x, tid = threadIdx.x;
    float v = x[(size_t)row * DD + tid];
    red[tid] = v;
    __syncthreads();
    for (int st = 128; st > 0; st >>= 1) {
        if (tid < st) red[tid] += red[tid + st];
        __syncthreads();
    }
    float mean = red[0] * (1.f / DD);
    __syncthreads();
    float d = v - mean;
    red[tid] = d * d;
    __syncthreads();
    for (int st = 128; st > 0; st >>= 1) {
        if (tid < st) red[tid] += red[tid + st];
        __syncthreads();
    }
    float var = red[0] * (1.f / DD);
    o[(size_t)row * DD + tid] = d / sqrtf(var + 1e-5f) * s[tid] + b[tid];
}

// ---------------------------------------------------------------------------
// Row L2-normalize (D=256)
// ---------------------------------------------------------------------------
__global__ __launch_bounds__(256) void l2norm_k(const float* __restrict__ in,
                                                float* __restrict__ out) {
    __shared__ float red[256];
    const int row = blockIdx.x, tid = threadIdx.x;
    float v = in[(size_t)row * DD + tid];
    red[tid] = v * v;
    __syncthreads();
    for (int st = 128; st > 0; st >>= 1) {
        if (tid < st) red[tid] += red[tid + st];
        __syncthreads();
    }
    float inv = 1.f / sqrtf(red[0]);
    out[(size_t)row * DD + tid] = v * inv;
}

// ---------------------------------------------------------------------------
// Top-96 pipeline over a sims chunk [CHQ rows x NCAND].
// Bucket index is monotone in sim value; equal values -> equal bucket, so
// {bucket > B1} + exact fp32 select inside bucket B1 == exact fp32 top-96 set.
// ---------------------------------------------------------------------------
__device__ inline int bucket_of(float s) {
    int b = (int)((s + 1.0f) * BSCALE);
    return b < 0 ? 0 : (b > NBUCK - 1 ? NBUCK - 1 : b);
}

// grid (NSEG, CHQ): per-block LDS histogram of a 12.5K-element segment,
// then merge non-zero bins into the per-query global histogram.
__global__ __launch_bounds__(256) void histl_k(const float* __restrict__ sims,
                                               unsigned* __restrict__ ghist) {
    __shared__ unsigned lh[NBUCK];
    const int q = blockIdx.y, tid = threadIdx.x;
    for (int i = tid; i < NBUCK; i += 256) lh[i] = 0;
    __syncthreads();
    const float4* r4 = (const float4*)(sims + (size_t)q * NCAND) + blockIdx.x * SEG4;
    for (int t = tid; t < SEG4; t += 256) {
        float4 v = r4[t];
        atomicAdd(&lh[bucket_of(v.x)], 1u);
        atomicAdd(&lh[bucket_of(v.y)], 1u);
        atomicAdd(&lh[bucket_of(v.z)], 1u);
        atomicAdd(&lh[bucket_of(v.w)], 1u);
    }
    __syncthreads();
    unsigned* h = ghist + (size_t)q * NBUCK;
    for (int i = tid; i < NBUCK; i += 256) {
        unsigned c = lh[i];
        if (c) atomicAdd(&h[i], c);
    }
}

// one block per query: find boundary bucket B1 (cum from top reaches >= 96)
__global__ __launch_bounds__(256) void thr_k(const unsigned* __restrict__ ghist,
                                             int* __restrict__ B1v,
                                             unsigned* __restrict__ cnt_def,
                                             unsigned* __restrict__ cnt_tie) {
    __shared__ unsigned part[256];
    const int q = blockIdx.x, tid = threadIdx.x;
    const unsigned* h = ghist + (size_t)q * NBUCK;
    unsigned s = 0;
#pragma unroll
    for (int i = 0; i < 16; ++i) s += h[tid * 16 + i];
    part[tid] = s;
    __syncthreads();
    if (tid == 0) {
        unsigned cum = 0;
        int seg = 0;
        for (int t = 255; t >= 0; --t) {
            if (cum + part[t] >= CC) { seg = t; break; }
            cum += part[t];
        }
        int b1 = seg * 16;
        for (int b = seg * 16 + 15; b >= seg * 16; --b) {
            if (cum + h[b] >= CC) { b1 = b; break; }
            cum += h[b];
        }
        B1v[q] = b1;
        cnt_def[q] = 0;
        cnt_tie[q] = 0;
    }
}

// grid (25, CHQ): emit definite winners (bucket > B1, count < 96 guaranteed)
// directly into the output slots; boundary-bucket ties into tie buffers.
__global__ __launch_bounds__(256) void compact_k(const float* __restrict__ sims,
                                                 const int* __restrict__ B1v,
                                                 unsigned* __restrict__ cnt_def,
                                                 unsigned* __restrict__ cnt_tie,
                                                 float* __restrict__ tieval,
                                                 int* __restrict__ tieidx,
                                                 int* __restrict__ idxout, int qo) {
    const int q = blockIdx.y, tid = threadIdx.x;
    const float4* r4 = (const float4*)(sims + (size_t)q * NCAND);
    const int b1 = B1v[q];
    int* myout = idxout + (size_t)(qo + q) * CC;
    float* tv = tieval + (size_t)q * TIECAP;
    int* tix = tieidx + (size_t)q * TIECAP;
    const int base4 = blockIdx.x * 1000;
    for (int t = tid; t < 1000; t += 256) {
        float4 v = r4[base4 + t];
        float vv[4] = {v.x, v.y, v.z, v.w};
        int j = (base4 + t) * 4;
#pragma unroll
        for (int u = 0; u < 4; ++u) {
            int b = bucket_of(vv[u]);
            if (b > b1) {
                unsigned p = atomicAdd(&cnt_def[q], 1u);
                myout[p] = j + u;
            } else if (b == b1) {
                unsigned p = atomicAdd(&cnt_tie[q], 1u);
                if (p < TIECAP) { tv[p] = vv[u]; tix[p] = j + u; }
            }
        }
    }
}

// one block per query: exact fp32 selection of remaining slots among ties
__global__ __launch_bounds__(256) void final_k(const unsigned* __restrict__ cnt_def,
                                               const unsigned* __restrict__ cnt_tie,
                                               float* __restrict__ tieval,
                                               const int* __restrict__ tieidx,
                                               int* __restrict__ idxout, int qo) {
    __shared__ float rv[256];
    __shared__ int rj[256];
    const int q = blockIdx.x, tid = threadIdx.x;
    const int base = (int)cnt_def[q];
    const int rem = CC - base;
    unsigned ct = cnt_tie[q];
    const int nt = (int)(ct < (unsigned)TIECAP ? ct : (unsigned)TIECAP);
    float* tv = tieval + (size_t)q * TIECAP;
    const int* tix = tieidx + (size_t)q * TIECAP;
    int* myout = idxout + (size_t)(qo + q) * CC;
    for (int r = 0; r < rem; ++r) {
        float bvv = -1e30f;
        int bj = -1;
        for (int t = tid; t < nt; t += 256)
            if (tv[t] > bvv) { bvv = tv[t]; bj = t; }
        rv[tid] = bvv;
        rj[tid] = bj;
        __syncthreads();
        for (int st = 128; st > 0; st >>= 1) {
            if (tid < st && rv[tid + st] > rv[tid]) { rv[tid] = rv[tid + st]; rj[tid] = rj[tid + st]; }
            __syncthreads();
        }
        if (tid == 0) {
            myout[base + r] = tix[rj[0]];
            tv[rj[0]] = -1e30f;
        }
        __syncthreads();
    }
}

// ---------------------------------------------------------------------------
// ctx[b,c,:] = candidate_k[idx[b,c],:] + label_emb[candidate_y[idx[b,c]],:]
// ---------------------------------------------------------------------------
__global__ __launch_bounds__(256) void ctx_k(const int* __restrict__ idx,
                                             const float* __restrict__ ck,
                                             const int* __restrict__ cy,
                                             const float* __restrict__ le,
                                             float* __restrict__ ctx) {
    const int row = blockIdx.x, tid = threadIdx.x;
    const int i = idx[row];
    const int y = cy[i];
    ctx[(size_t)row * DD + tid] = ck[(size_t)i * DD + tid] + le[(size_t)y * DD + tid];
}

// ---------------------------------------------------------------------------
// Wf[(h*256+e), f] = sum_d wv[e, h*32+d] * wo[h*32+d, f]
// ---------------------------------------------------------------------------
__global__ __launch_bounds__(256) void wfuse_k(const float* __restrict__ wv,
                                               const float* __restrict__ wo,
                                               float* __restrict__ Wf) {
    const int r = blockIdx.x;          // h*256 + e
    const int h = r >> 8, e = r & 255;
    const int f = threadIdx.x;
    float acc = 0.f;
#pragma unroll
    for (int d = 0; d < DH; ++d)
        acc += wv[(size_t)e * DD + h * DH + d] * wo[(size_t)(h * DH + d) * DD + f];
    Wf[(size_t)r * DD + f] = acc;
}

// c0[f] = bv @ wo + bo
__global__ __launch_bounds__(256) void c0_k(const float* __restrict__ bv,
                                            const float* __restrict__ wo,
                                            const float* __restrict__ bo,
                                            float* __restrict__ c0) {
    const int f = threadIdx.x;
    float acc = bo[f];
    for (int r = 0; r < DD; ++r) acc += bv[r] * wo[(size_t)r * DD + f];
    c0[f] = acc;
}

// ---------------------------------------------------------------------------
// Fused attention (per batch row b)
// ---------------------------------------------------------------------------
__global__ __launch_bounds__(256) void attn_k(const float* __restrict__ qb,
                                              const float* __restrict__ wk,
                                              const float* __restrict__ ctx,
                                              float* __restrict__ mout) {
    __shared__ float qs[DD];
    __shared__ float ts[HH * DD];
    __shared__ float ss[HH * CC];
    const int b = blockIdx.x, tid = threadIdx.x;
    qs[tid] = qb[(size_t)b * DD + tid];
    __syncthreads();

    for (int idx = tid; idx < HH * DD; idx += 256) {
        const int h = idx >> 8, e = idx & 255;
        float acc = 0.f;
#pragma unroll
        for (int d = 0; d < DH; ++d) acc += qs[h * DH + d] * wk[(size_t)e * DD + h * DH + d];
        ts[idx] = acc;
    }
    __syncthreads();

    const float scale = 0.17677669529663687f;  // 1/sqrt(32)
    const float* cb = ctx + (size_t)b * CC * DD;
    for (int o = tid; o < HH * CC; o += 256) {
        const int c = o >> 3, h = o & 7;
        const float* cr = cb + (size_t)c * DD;
        const float* th = ts + h * DD;
        float acc = 0.f;
        for (int e = 0; e < DD; ++e) acc += cr[e] * th[e];
        ss[h * CC + c] = acc * scale;
    }
    __syncthreads();

    if (tid < HH) {
        const int h = tid;
        float mx = -1e30f;
        for (int c = 0; c < CC; ++c) mx = fmaxf(mx, ss[h * CC + c]);
        float sum = 0.f;
        for (int c = 0; c < CC; ++c) {
            float e = expf(ss[h * CC + c] - mx);
            ss[h * CC + c] = e;
            sum += e;
        }
        float inv = 1.f / sum;
        for (int c = 0; c < CC; ++c) ss[h * CC + c] *= inv;
    }
    __syncthreads();

    float acc[HH] = {};
    for (int c = 0; c < CC; ++c) {
        float v = cb[(size_t)c * DD + tid];
#pragma unroll
        for (int h = 0; h < HH; ++h) acc[h] += ss[h * CC + c] * v;
    }
#pragma unroll
    for (int h = 0; h < HH; ++h) mout[(size_t)b * (HH * DD) + h * DD + tid] = acc[h];
}

// ---------------------------------------------------------------------------
// Host launcher
// ---------------------------------------------------------------------------
extern "C" void kernel_launch(void* const* d_in, const int* in_sizes, int n_in,
                              void* d_out, int out_size, void* d_ws, size_t ws_size,
                              hipStream_t stream) {
    (void)in_sizes; (void)n_in; (void)out_size; (void)ws_size;
    const float* x_num  = (const float*)d_in[0];
    const float* cand_k = (const float*)d_in[1];
    const int*   cand_y = (const int*)d_in[2];
    const float* enc_w0 = (const float*)d_in[3];
    const float* enc_b0 = (const float*)d_in[4];
    const float* enc_ln_s = (const float*)d_in[5];
    const float* enc_ln_b = (const float*)d_in[6];
    const float* enc_w1 = (const float*)d_in[7];
    const float* enc_b1 = (const float*)d_in[8];
    const float* enc_w2 = (const float*)d_in[9];
    const float* enc_b2 = (const float*)d_in[10];
    const float* label_emb = (const float*)d_in[11];
    const float* ln1_s = (const float*)d_in[12];
    const float* ln1_b = (const float*)d_in[13];
    const float* wq = (const float*)d_in[14];
    const float* bq = (const float*)d_in[15];
    const float* wk = (const float*)d_in[16];
    // d_in[17] = bk : constant shift per (b,h) inside softmax -> drops out
    const float* wv = (const float*)d_in[18];
    const float* bv = (const float*)d_in[19];
    const float* wo = (const float*)d_in[20];
    const float* bo = (const float*)d_in[21];
    const float* ln2_s = (const float*)d_in[22];
    const float* ln2_b = (const float*)d_in[23];
    const float* fw1 = (const float*)d_in[24];
    const float* fb1 = (const float*)d_in[25];
    const float* fw2 = (const float*)d_in[26];
    const float* fb2 = (const float*)d_in[27];
    const float* head_w = (const float*)d_in[28];
    const float* head_b = (const float*)d_in[29];
    float* out = (float*)d_out;

    char* ws = (char*)d_ws;
    size_t off = 0;
    auto alloc = [&](size_t bytes) -> void* {
        void* p = ws + off;
        off += (bytes + 255) & ~(size_t)255;
        return p;
    };
    float* big  = (float*)alloc((size_t)CHQ * NCAND * 4);   // sims chunk, reused as ctx
    float* h0   = (float*)alloc((size_t)BB * DD * 4);
    float* h1   = (float*)alloc((size_t)BB * DENC * 4);
    float* hln  = (float*)alloc((size_t)BB * DD * 4);
    float* x    = (float*)alloc((size_t)BB * DD * 4);       // query, then residual stream
    float* qbuf = (float*)alloc((size_t)BB * DD * 4);
    int*   idxb = (int*)alloc((size_t)BB * CC * 4);
    float* mbuf = (float*)alloc((size_t)BB * HH * DD * 4);
    float* Wf   = (float*)alloc((size_t)HH * DD * DD * 4);
    float* c0   = (float*)alloc(DD * 4);
    float* ffh  = (float*)alloc((size_t)BB * DFF * 4);
    unsigned* ghist  = (unsigned*)alloc((size_t)CHQ * NBUCK * 4);
    int*      B1v    = (int*)alloc((size_t)CHQ * 4);
    unsigned* cntd   = (unsigned*)alloc((size_t)CHQ * 4);
    unsigned* cntt   = (unsigned*)alloc((size_t)CHQ * 4);
    float*    tieval = (float*)alloc((size_t)CHQ * TIECAP * 4);
    int*      tieidx = (int*)alloc((size_t)CHQ * TIECAP * 4);
    float* ctx  = big;

    dim3 blk(256);

    // ---- encoder ----
    gemm_k<false, false, false><<<dim3(DD / BN, BB / BM), blk, 0, stream>>>(
        x_num, enc_w0, enc_b0, nullptr, h0, BB, DD, NNUM);
    for (int i = 0; i < NBLK; ++i) {
        ln_k<<<BB, blk, 0, stream>>>(h0, enc_ln_s + i * DD, enc_ln_b + i * DD, hln);
        gemm_k<false, true, false><<<dim3(DENC / BN, BB / BM), blk, 0, stream>>>(
            hln, enc_w1 + (size_t)i * DD * DENC, enc_b1 + i * DENC, nullptr, h1, BB, DENC, DD);
        gemm_k<false, false, false><<<dim3(DD / BN, BB / BM), blk, 0, stream>>>(
            h1, enc_w2 + (size_t)i * DENC * DD, enc_b2 + i * DD, nullptr, h0, BB, DD, DENC);
    }
    l2norm_k<<<BB, blk, 0, stream>>>(h0, x);  // x = query

    // ---- retrieval: sims (fp32, chunked) + exact top-96 (bucket select) ----
    for (int ci = 0; ci < BB / CHQ; ++ci) {
        const int qo = ci * CHQ;
        hipMemsetAsync(ghist, 0, (size_t)CHQ * NBUCK * 4, stream);
        gemm_k<true, false, false><<<dim3((NCAND + BN - 1) / BN, CHQ / BM), blk, 0, stream>>>(
            x + (size_t)qo * DD, cand_k, nullptr, nullptr, big, CHQ, NCAND, DD);
        histl_k<<<dim3(NSEG, CHQ), blk, 0, stream>>>(big, ghist);
        thr_k<<<CHQ, blk, 0, stream>>>(ghist, B1v, cntd, cntt);
        compact_k<<<dim3(25, CHQ), blk, 0, stream>>>(big, B1v, cntd, cntt, tieval, tieidx, idxb, qo);
        final_k<<<CHQ, blk, 0, stream>>>(cntd, cntt, tieval, tieidx, idxb, qo);
    }
    ctx_k<<<BB * CC, blk, 0, stream>>>(idxb, cand_k, cand_y, label_emb, ctx);

    // ---- transformer mixer (associativity-restructured attention) ----
    for (int i = 0; i < NBLK; ++i) {
        const size_t W = (size_t)i * DD * DD;
        ln_k<<<BB, blk, 0, stream>>>(x, ln1_s + i * DD, ln1_b + i * DD, hln);
        gemm_k<false, false, false><<<dim3(DD / BN, BB / BM), blk, 0, stream>>>(
            hln, wq + W, bq + i * DD, nullptr, qbuf, BB, DD, DD);
        wfuse_k<<<HH * DD, blk, 0, stream>>>(wv + W, wo + W, Wf);
        c0_k<<<1, blk, 0, stream>>>(bv + i * DD, wo + W, bo + i * DD, c0);
        attn_k<<<BB, blk, 0, stream>>>(qbuf, wk + W, ctx, mbuf);
        gemm_k<false, false, true><<<dim3(DD / BN, BB / BM), blk, 0, stream>>>(
            mbuf, Wf, c0, x, x, BB, DD, HH * DD);
        ln_k<<<BB, blk, 0, stream>>>(x, ln2_s + i * DD, ln2_b + i * DD, hln);
        gemm_k<false, true, false><<<dim3(DFF / BN, BB / BM), blk, 0, stream>>>(
            hln, fw1 + (size_t)i * DD * DFF, fb1 + i * DFF, nullptr, ffh, BB, DFF, DD);
        gemm_k<false, false, true><<<dim3(DD / BN, BB / BM), blk, 0, stream>>>(
            ffh, fw2 + (size_t)i * DFF * DD, fb2 + i * DD, x, x, BB, DD, DFF);
    }

    // ---- head ----
    gemm_k<false, false, false><<<dim3(1, BB / BM), blk, 0, stream>>>(
        x, head_w, head_b, nullptr, out, BB, NCLS, DD);
}

// Round 6
// 2399.658 us; speedup vs baseline: 3.2746x; 1.1061x over previous
//
#include <hip/hip_runtime.h>
#include <hip/hip_bf16.h>
#include <math.h>

// ---------------------------------------------------------------------------
// Dims (fixed by the reference)
// ---------------------------------------------------------------------------
#define BB    1024      // batch
#define NCAND 100000    // candidates
#define DD    256       // d_main
#define CC    96        // context size
#define HH    8         // heads
#define DH    32        // head dim
#define NBLK  2
#define DENC  512
#define DFF   1024
#define NNUM  64
#define NCLS  10
#define CHQ   256       // query chunk for sims buffer

// top-k select: fixed-point buckets over sims in [-1,1]
#define NBUCK  4096
#define BSCALE 2048.0f
#define TIECAP 2048
#define NSEG   8
#define SEG4   3125     // float4 per segment = NCAND/4/NSEG
#define MARGIN 20       // bucket margin covering worst-case bf16 sims error (2*eps ~ 16 buckets)

typedef __attribute__((ext_vector_type(8))) short s16x8;
typedef __attribute__((ext_vector_type(4))) float f32x4;

// ---------------------------------------------------------------------------
// Generic fp32 tiled GEMM: C[M,N] = act(A[M,K] @ B + bias) [+ res]
// B is K x N row-major. M % 64 == 0, K % 16 == 0. N masked.
// ---------------------------------------------------------------------------
#define BM 64
#define BN 64
#define BK 16

template <bool RELU, bool RES>
__global__ __launch_bounds__(256) void gemm_k(const float* __restrict__ A,
                                              const float* __restrict__ B,
                                              const float* __restrict__ bias,
                                              const float* __restrict__ res,
                                              float* __restrict__ C,
                                              int M, int N, int K) {
    __shared__ __align__(16) float As[BK][BM + 4];
    __shared__ __align__(16) float Bs[BK][BN + 4];
    const int tid = threadIdx.x;
    const int bm = blockIdx.y * BM;
    const int bn = blockIdx.x * BN;
    const int tm = (tid >> 4) << 2;   // 0..60
    const int tn = (tid & 15) << 2;   // 0..60

    float acc[4][4] = {};

    for (int k0 = 0; k0 < K; k0 += BK) {
#pragma unroll
        for (int l = 0; l < 4; ++l) {
            int lin = l * 256 + tid;
            int m = lin >> 4;
            int k = lin & 15;
            As[k][m] = A[(size_t)(bm + m) * K + k0 + k];
        }
#pragma unroll
        for (int l = 0; l < 4; ++l) {
            int lin = l * 256 + tid;
            int k = lin >> 6;
            int n = lin & 63;
            int gn = bn + n;
            Bs[k][n] = (gn < N) ? B[(size_t)(k0 + k) * N + gn] : 0.f;
        }
        __syncthreads();
#pragma unroll
        for (int k = 0; k < BK; ++k) {
            float4 a4 = *(const float4*)&As[k][tm];
            float4 b4 = *(const float4*)&Bs[k][tn];
            float av[4] = {a4.x, a4.y, a4.z, a4.w};
            float bv[4] = {b4.x, b4.y, b4.z, b4.w};
#pragma unroll
            for (int i = 0; i < 4; ++i)
#pragma unroll
                for (int j = 0; j < 4; ++j) acc[i][j] += av[i] * bv[j];
        }
        __syncthreads();
    }

#pragma unroll
    for (int i = 0; i < 4; ++i) {
        int r = bm + tm + i;
#pragma unroll
        for (int j = 0; j < 4; ++j) {
            int c = bn + tn + j;
            if (c < N) {
                float v = acc[i][j];
                if (bias) v += bias[c];
                if (RELU) v = fmaxf(v, 0.f);
                if (RES) v += res[(size_t)r * N + c];
                C[(size_t)r * N + c] = v;
            }
        }
    }
}

// ---------------------------------------------------------------------------
// fp32 -> bf16 (round-to-nearest-even), 4 elements per thread
// ---------------------------------------------------------------------------
__device__ inline short f2bf(float f) {
    unsigned u = __float_as_uint(f);
    unsigned r = 0x7fffu + ((u >> 16) & 1u);
    return (short)((u + r) >> 16);
}

__global__ __launch_bounds__(256) void cvt_k(const float* __restrict__ in,
                                             short* __restrict__ out, int n4) {
    int i = blockIdx.x * 256 + threadIdx.x;
    if (i < n4) {
        float4 v = ((const float4*)in)[i];
        short4 o;
        o.x = f2bf(v.x); o.y = f2bf(v.y); o.z = f2bf(v.z); o.w = f2bf(v.w);
        ((short4*)out)[i] = o;
    }
}

// ---------------------------------------------------------------------------
// Sims GEMM on matrix cores: C[m][n] = sum_k A[m][k]*B[n][k], bf16 in, fp32 out.
// A: [CHQ][DD] bf16 (queries chunk), B: [NCAND][DD] bf16. Per-wave 64x64 tile,
// no LDS (B is L2/L3-resident). mfma_f32_16x16x32_bf16; frag layouts per the
// m89-verified mapping (A: row=lane&15,k=(lane>>4)*8+j ; C: col=lane&15,
// row=(lane>>4)*4+reg).
// ---------------------------------------------------------------------------
__global__ __launch_bounds__(256) void simsmm_k(const short* __restrict__ A,
                                                const short* __restrict__ B,
                                                float* __restrict__ C) {
    const int lane = threadIdx.x & 63;
    const int wid  = threadIdx.x >> 6;
    const int m0 = blockIdx.y * 64;
    const int n0 = blockIdx.x * 256 + wid * 64;
    const int lg = lane >> 4;          // 0..3
    const int lr = lane & 15;

    f32x4 acc[4][4];
#pragma unroll
    for (int i = 0; i < 4; ++i)
#pragma unroll
        for (int j = 0; j < 4; ++j) acc[i][j] = (f32x4){0.f, 0.f, 0.f, 0.f};

    for (int k0 = 0; k0 < DD; k0 += 32) {
        const int kb = k0 + lg * 8;
        s16x8 a[4], b[4];
#pragma unroll
        for (int i = 0; i < 4; ++i)
            a[i] = *(const s16x8*)(A + (size_t)(m0 + 16 * i + lr) * DD + kb);
#pragma unroll
        for (int j = 0; j < 4; ++j) {
            int rb = n0 + 16 * j + lr;
            rb = rb < NCAND ? rb : 0;
            b[j] = *(const s16x8*)(B + (size_t)rb * DD + kb);
        }
#pragma unroll
        for (int i = 0; i < 4; ++i)
#pragma unroll
            for (int j = 0; j < 4; ++j)
                acc[i][j] = __builtin_amdgcn_mfma_f32_16x16x32_bf16(a[i], b[j], acc[i][j], 0, 0, 0);
    }

#pragma unroll
    for (int i = 0; i < 4; ++i) {
        const int row = m0 + 16 * i + lg * 4;
#pragma unroll
        for (int j = 0; j < 4; ++j) {
            const int col = n0 + 16 * j + lr;
            if (col < NCAND) {
#pragma unroll
                for (int r = 0; r < 4; ++r)
                    C[(size_t)(row + r) * NCAND + col] = acc[i][j][r];
            }
        }
    }
}

// ---------------------------------------------------------------------------
// LayerNorm over D=256 (one block per row)
// ---------------------------------------------------------------------------
__global__ __launch_bounds__(256) void ln_k(const float* __restrict__ x,
                                            const float* __restrict__ s,
                                            const float* __restrict__ b,
                                            float* __restrict__ o) {
    __shared__ float red[256];
    const int row = blockIdx.x, tid = threadIdx.x;
    float v = x[(size_t)row * DD + tid];
    red[tid] = v;
    __syncthreads();
    for (int st = 128; st > 0; st >>= 1) {
        if (tid < st) red[tid] += red[tid + st];
        __syncthreads();
    }
    float mean = red[0] * (1.f / DD);
    __syncthreads();
    float d = v - mean;
    red[tid] = d * d;
    __syncthreads();
    for (int st = 128; st > 0; st >>= 1) {
        if (tid < st) red[tid] += red[tid + st];
        __syncthreads();
    }
    float var = red[0] * (1.f / DD);
    o[(size_t)row * DD + tid] = d / sqrtf(var + 1e-5f) * s[tid] + b[tid];
}

// ---------------------------------------------------------------------------
// Row L2-normalize (D=256)
// ---------------------------------------------------------------------------
__global__ __launch_bounds__(256) void l2norm_k(const float* __restrict__ in,
                                                float* __restrict__ out) {
    __shared__ float red[256];
    const int row = blockIdx.x, tid = threadIdx.x;
    float v = in[(size_t)row * DD + tid];
    red[tid] = v * v;
    __syncthreads();
    for (int st = 128; st > 0; st >>= 1) {
        if (tid < st) red[tid] += red[tid + st];
        __syncthreads();
    }
    float inv = 1.f / sqrtf(red[0]);
    out[(size_t)row * DD + tid] = v * inv;
}

// ---------------------------------------------------------------------------
// Top-96 select over approx sims (bucketed), exact-verified at the boundary.
// definite: bucket > B1+MARGIN  (provably in exact top-96)
// tie:      bucket in [B1-MARGIN, B1+MARGIN] -> exact fp32 re-dot in final_k
// ---------------------------------------------------------------------------
__device__ inline int bucket_of(float s) {
    int b = (int)((s + 1.0f) * BSCALE);
    return b < 0 ? 0 : (b > NBUCK - 1 ? NBUCK - 1 : b);
}

// grid (NSEG, CHQ): per-block LDS histogram of a 12.5K-element segment
__global__ __launch_bounds__(256) void histl_k(const float* __restrict__ sims,
                                               unsigned* __restrict__ ghist) {
    __shared__ unsigned lh[NBUCK];
    const int q = blockIdx.y, tid = threadIdx.x;
    for (int i = tid; i < NBUCK; i += 256) lh[i] = 0;
    __syncthreads();
    const float4* r4 = (const float4*)(sims + (size_t)q * NCAND) + blockIdx.x * SEG4;
    for (int t = tid; t < SEG4; t += 256) {
        float4 v = r4[t];
        atomicAdd(&lh[bucket_of(v.x)], 1u);
        atomicAdd(&lh[bucket_of(v.y)], 1u);
        atomicAdd(&lh[bucket_of(v.z)], 1u);
        atomicAdd(&lh[bucket_of(v.w)], 1u);
    }
    __syncthreads();
    unsigned* h = ghist + (size_t)q * NBUCK;
    for (int i = tid; i < NBUCK; i += 256) {
        unsigned c = lh[i];
        if (c) atomicAdd(&h[i], c);
    }
}

// one block per query: find boundary bucket B1 (cum from top reaches >= 96)
__global__ __launch_bounds__(256) void thr_k(const unsigned* __restrict__ ghist,
                                             int* __restrict__ B1v,
                                             unsigned* __restrict__ cnt_def,
                                             unsigned* __restrict__ cnt_tie) {
    __shared__ unsigned part[256];
    const int q = blockIdx.x, tid = threadIdx.x;
    const unsigned* h = ghist + (size_t)q * NBUCK;
    unsigned s = 0;
#pragma unroll
    for (int i = 0; i < 16; ++i) s += h[tid * 16 + i];
    part[tid] = s;
    __syncthreads();
    if (tid == 0) {
        unsigned cum = 0;
        int seg = 0;
        for (int t = 255; t >= 0; --t) {
            if (cum + part[t] >= CC) { seg = t; break; }
            cum += part[t];
        }
        int b1 = seg * 16;
        for (int b = seg * 16 + 15; b >= seg * 16; --b) {
            if (cum + h[b] >= CC) { b1 = b; break; }
            cum += h[b];
        }
        B1v[q] = b1;
        cnt_def[q] = 0;
        cnt_tie[q] = 0;
    }
}

// grid (25, CHQ): emit definite winners and boundary ties
__global__ __launch_bounds__(256) void compact_k(const float* __restrict__ sims,
                                                 const int* __restrict__ B1v,
                                                 unsigned* __restrict__ cnt_def,
                                                 unsigned* __restrict__ cnt_tie,
                                                 float* __restrict__ tieval,
                                                 int* __restrict__ tieidx,
                                                 int* __restrict__ idxout, int qo) {
    const int q = blockIdx.y, tid = threadIdx.x;
    const float4* r4 = (const float4*)(sims + (size_t)q * NCAND);
    const int b1 = B1v[q];
    int* myout = idxout + (size_t)(qo + q) * CC;
    float* tv = tieval + (size_t)q * TIECAP;
    int* tix = tieidx + (size_t)q * TIECAP;
    const int base4 = blockIdx.x * 1000;
    for (int t = tid; t < 1000; t += 256) {
        float4 v = r4[base4 + t];
        float vv[4] = {v.x, v.y, v.z, v.w};
        int j = (base4 + t) * 4;
#pragma unroll
        for (int u = 0; u < 4; ++u) {
            int b = bucket_of(vv[u]);
            if (b > b1 + MARGIN) {
                unsigned p = atomicAdd(&cnt_def[q], 1u);
                myout[p] = j + u;
            } else if (b >= b1 - MARGIN) {
                unsigned p = atomicAdd(&cnt_tie[q], 1u);
                if (p < TIECAP) { tv[p] = vv[u]; tix[p] = j + u; }
            }
        }
    }
}

// one block per query: exact fp32 re-dot of ties, then exact selection
__global__ __launch_bounds__(256) void final_k(const float* __restrict__ xq,
                                               const float* __restrict__ ck,
                                               const unsigned* __restrict__ cnt_def,
                                               const unsigned* __restrict__ cnt_tie,
                                               float* __restrict__ tieval,
                                               const int* __restrict__ tieidx,
                                               int* __restrict__ idxout, int qo) {
    __shared__ float xs[DD];
    __shared__ float rv[256];
    __shared__ int rj[256];
    const int q = blockIdx.x, tid = threadIdx.x;
    const int lane = tid & 63, wav = tid >> 6;
    xs[tid] = xq[(size_t)(qo + q) * DD + tid];
    __syncthreads();
    const int base = (int)cnt_def[q];
    const int rem = CC - base;
    unsigned ct = cnt_tie[q];
    const int nt = (int)(ct < (unsigned)TIECAP ? ct : (unsigned)TIECAP);
    float* tv = tieval + (size_t)q * TIECAP;
    const int* tix = tieidx + (size_t)q * TIECAP;
    int* myout = idxout + (size_t)(qo + q) * CC;

    // exact fp32 dots for tie candidates (wave-cooperative)
    for (int t = wav; t < nt; t += 4) {
        const float* row = ck + (size_t)tix[t] * DD;
        float s = 0.f;
#pragma unroll
        for (int e = 0; e < 4; ++e) s += row[lane + 64 * e] * xs[lane + 64 * e];
        for (int off = 32; off > 0; off >>= 1) s += __shfl_down(s, off);
        if (lane == 0) tv[t] = s;
    }
    __syncthreads();

    for (int r = 0; r < rem; ++r) {
        float bvv = -1e30f;
        int bj = -1;
        for (int t = tid; t < nt; t += 256)
            if (tv[t] > bvv) { bvv = tv[t]; bj = t; }
        rv[tid] = bvv;
        rj[tid] = bj;
        __syncthreads();
        for (int st = 128; st > 0; st >>= 1) {
            if (tid < st && rv[tid + st] > rv[tid]) { rv[tid] = rv[tid + st]; rj[tid] = rj[tid + st]; }
            __syncthreads();
        }
        if (tid == 0) {
            myout[base + r] = tix[rj[0]];
            tv[rj[0]] = -1e30f;
        }
        __syncthreads();
    }
}

// ---------------------------------------------------------------------------
// ctx[b,c,:] = candidate_k[idx[b,c],:] + label_emb[candidate_y[idx[b,c]],:]
// ---------------------------------------------------------------------------
__global__ __launch_bounds__(256) void ctx_k(const int* __restrict__ idx,
                                             const float* __restrict__ ck,
                                             const int* __restrict__ cy,
                                             const float* __restrict__ le,
                                             float* __restrict__ ctx) {
    const int row = blockIdx.x, tid = threadIdx.x;
    const int i = idx[row];
    const int y = cy[i];
    ctx[(size_t)row * DD + tid] = ck[(size_t)i * DD + tid] + le[(size_t)y * DD + tid];
}

// ---------------------------------------------------------------------------
// Wf[(h*256+e), f] = sum_d wv[e, h*32+d] * wo[h*32+d, f]
// ---------------------------------------------------------------------------
__global__ __launch_bounds__(256) void wfuse_k(const float* __restrict__ wv,
                                               const float* __restrict__ wo,
                                               float* __restrict__ Wf) {
    const int r = blockIdx.x;          // h*256 + e
    const int h = r >> 8, e = r & 255;
    const int f = threadIdx.x;
    float acc = 0.f;
#pragma unroll
    for (int d = 0; d < DH; ++d)
        acc += wv[(size_t)e * DD + h * DH + d] * wo[(size_t)(h * DH + d) * DD + f];
    Wf[(size_t)r * DD + f] = acc;
}

// c0[f] = bv @ wo + bo
__global__ __launch_bounds__(256) void c0_k(const float* __restrict__ bv,
                                            const float* __restrict__ wo,
                                            const float* __restrict__ bo,
                                            float* __restrict__ c0) {
    const int f = threadIdx.x;
    float acc = bo[f];
    for (int r = 0; r < DD; ++r) acc += bv[r] * wo[(size_t)r * DD + f];
    c0[f] = acc;
}

// ---------------------------------------------------------------------------
// Fused attention (per batch row b)
// ---------------------------------------------------------------------------
__global__ __launch_bounds__(256) void attn_k(const float* __restrict__ qb,
                                              const float* __restrict__ wk,
                                              const float* __restrict__ ctx,
                                              float* __restrict__ mout) {
    __shared__ float qs[DD];
    __shared__ float ts[HH * DD];
    __shared__ float ss[HH * CC];
    const int b = blockIdx.x, tid = threadIdx.x;
    qs[tid] = qb[(size_t)b * DD + tid];
    __syncthreads();

    for (int idx = tid; idx < HH * DD; idx += 256) {
        const int h = idx >> 8, e = idx & 255;
        float acc = 0.f;
#pragma unroll
        for (int d = 0; d < DH; ++d) acc += qs[h * DH + d] * wk[(size_t)e * DD + h * DH + d];
        ts[idx] = acc;
    }
    __syncthreads();

    const float scale = 0.17677669529663687f;  // 1/sqrt(32)
    const float* cb = ctx + (size_t)b * CC * DD;
    for (int o = tid; o < HH * CC; o += 256) {
        const int c = o >> 3, h = o & 7;
        const float* cr = cb + (size_t)c * DD;
        const float* th = ts + h * DD;
        float acc = 0.f;
        for (int e = 0; e < DD; ++e) acc += cr[e] * th[e];
        ss[h * CC + c] = acc * scale;
    }
    __syncthreads();

    if (tid < HH) {
        const int h = tid;
        float mx = -1e30f;
        for (int c = 0; c < CC; ++c) mx = fmaxf(mx, ss[h * CC + c]);
        float sum = 0.f;
        for (int c = 0; c < CC; ++c) {
            float e = expf(ss[h * CC + c] - mx);
            ss[h * CC + c] = e;
            sum += e;
        }
        float inv = 1.f / sum;
        for (int c = 0; c < CC; ++c) ss[h * CC + c] *= inv;
    }
    __syncthreads();

    float acc[HH] = {};
    for (int c = 0; c < CC; ++c) {
        float v = cb[(size_t)c * DD + tid];
#pragma unroll
        for (int h = 0; h < HH; ++h) acc[h] += ss[h * CC + c] * v;
    }
#pragma unroll
    for (int h = 0; h < HH; ++h) mout[(size_t)b * (HH * DD) + h * DD + tid] = acc[h];
}

// ---------------------------------------------------------------------------
// Host launcher
// ---------------------------------------------------------------------------
extern "C" void kernel_launch(void* const* d_in, const int* in_sizes, int n_in,
                              void* d_out, int out_size, void* d_ws, size_t ws_size,
                              hipStream_t stream) {
    (void)in_sizes; (void)n_in; (void)out_size; (void)ws_size;
    const float* x_num  = (const float*)d_in[0];
    const float* cand_k = (const float*)d_in[1];
    const int*   cand_y = (const int*)d_in[2];
    const float* enc_w0 = (const float*)d_in[3];
    const float* enc_b0 = (const float*)d_in[4];
    const float* enc_ln_s = (const float*)d_in[5];
    const float* enc_ln_b = (const float*)d_in[6];
    const float* enc_w1 = (const float*)d_in[7];
    const float* enc_b1 = (const float*)d_in[8];
    const float* enc_w2 = (const float*)d_in[9];
    const float* enc_b2 = (const float*)d_in[10];
    const float* label_emb = (const float*)d_in[11];
    const float* ln1_s = (const float*)d_in[12];
    const float* ln1_b = (const float*)d_in[13];
    const float* wq = (const float*)d_in[14];
    const float* bq = (const float*)d_in[15];
    const float* wk = (const float*)d_in[16];
    // d_in[17] = bk : constant shift per (b,h) inside softmax -> drops out
    const float* wv = (const float*)d_in[18];
    const float* bv = (const float*)d_in[19];
    const float* wo = (const float*)d_in[20];
    const float* bo = (const float*)d_in[21];
    const float* ln2_s = (const float*)d_in[22];
    const float* ln2_b = (const float*)d_in[23];
    const float* fw1 = (const float*)d_in[24];
    const float* fb1 = (const float*)d_in[25];
    const float* fw2 = (const float*)d_in[26];
    const float* fb2 = (const float*)d_in[27];
    const float* head_w = (const float*)d_in[28];
    const float* head_b = (const float*)d_in[29];
    float* out = (float*)d_out;

    char* ws = (char*)d_ws;
    size_t off = 0;
    auto alloc = [&](size_t bytes) -> void* {
        void* p = ws + off;
        off += (bytes + 255) & ~(size_t)255;
        return p;
    };
    float* big  = (float*)alloc((size_t)CHQ * NCAND * 4);   // sims chunk, reused as ctx
    float* h0   = (float*)alloc((size_t)BB * DD * 4);
    float* h1   = (float*)alloc((size_t)BB * DENC * 4);
    float* hln  = (float*)alloc((size_t)BB * DD * 4);
    float* x    = (float*)alloc((size_t)BB * DD * 4);       // query, then residual stream
    float* qbuf = (float*)alloc((size_t)BB * DD * 4);
    int*   idxb = (int*)alloc((size_t)BB * CC * 4);
    float* mbuf = (float*)alloc((size_t)BB * HH * DD * 4);
    float* Wf   = (float*)alloc((size_t)HH * DD * DD * 4);
    float* c0   = (float*)alloc(DD * 4);
    float* ffh  = (float*)alloc((size_t)BB * DFF * 4);
    unsigned* ghist  = (unsigned*)alloc((size_t)CHQ * NBUCK * 4);
    int*      B1v    = (int*)alloc((size_t)CHQ * 4);
    unsigned* cntd   = (unsigned*)alloc((size_t)CHQ * 4);
    unsigned* cntt   = (unsigned*)alloc((size_t)CHQ * 4);
    float*    tieval = (float*)alloc((size_t)CHQ * TIECAP * 4);
    int*      tieidx = (int*)alloc((size_t)CHQ * TIECAP * 4);
    short*    ckbf   = (short*)alloc((size_t)NCAND * DD * 2);
    short*    xbf    = (short*)alloc((size_t)BB * DD * 2);
    float* ctx  = big;

    dim3 blk(256);

    // ---- candidate_k -> bf16 (once) ----
    cvt_k<<<(NCAND * DD / 4 + 255) / 256, blk, 0, stream>>>(cand_k, ckbf, NCAND * DD / 4);

    // ---- encoder ----
    gemm_k<false, false><<<dim3(DD / BN, BB / BM), blk, 0, stream>>>(
        x_num, enc_w0, enc_b0, nullptr, h0, BB, DD, NNUM);
    for (int i = 0; i < NBLK; ++i) {
        ln_k<<<BB, blk, 0, stream>>>(h0, enc_ln_s + i * DD, enc_ln_b + i * DD, hln);
        gemm_k<true, false><<<dim3(DENC / BN, BB / BM), blk, 0, stream>>>(
            hln, enc_w1 + (size_t)i * DD * DENC, enc_b1 + i * DENC, nullptr, h1, BB, DENC, DD);
        gemm_k<false, false><<<dim3(DD / BN, BB / BM), blk, 0, stream>>>(
            h1, enc_w2 + (size_t)i * DENC * DD, enc_b2 + i * DD, nullptr, h0, BB, DD, DENC);
    }
    l2norm_k<<<BB, blk, 0, stream>>>(h0, x);  // x = query (fp32, exact)
    cvt_k<<<(BB * DD / 4 + 255) / 256, blk, 0, stream>>>(x, xbf, BB * DD / 4);

    // ---- retrieval: bf16-MFMA sims + margin-verified exact top-96 ----
    for (int ci = 0; ci < BB / CHQ; ++ci) {
        const int qo = ci * CHQ;
        hipMemsetAsync(ghist, 0, (size_t)CHQ * NBUCK * 4, stream);
        simsmm_k<<<dim3((NCAND + 255) / 256, CHQ / 64), blk, 0, stream>>>(
            xbf + (size_t)qo * DD, ckbf, big);
        histl_k<<<dim3(NSEG, CHQ), blk, 0, stream>>>(big, ghist);
        thr_k<<<CHQ, blk, 0, stream>>>(ghist, B1v, cntd, cntt);
        compact_k<<<dim3(25, CHQ), blk, 0, stream>>>(big, B1v, cntd, cntt, tieval, tieidx, idxb, qo);
        final_k<<<CHQ, blk, 0, stream>>>(x, cand_k, cntd, cntt, tieval, tieidx, idxb, qo);
    }
    ctx_k<<<BB * CC, blk, 0, stream>>>(idxb, cand_k, cand_y, label_emb, ctx);

    // ---- transformer mixer (associativity-restructured attention) ----
    for (int i = 0; i < NBLK; ++i) {
        const size_t W = (size_t)i * DD * DD;
        ln_k<<<BB, blk, 0, stream>>>(x, ln1_s + i * DD, ln1_b + i * DD, hln);
        gemm_k<false, false><<<dim3(DD / BN, BB / BM), blk, 0, stream>>>(
            hln, wq + W, bq + i * DD, nullptr, qbuf, BB, DD, DD);
        wfuse_k<<<HH * DD, blk, 0, stream>>>(wv + W, wo + W, Wf);
        c0_k<<<1, blk, 0, stream>>>(bv + i * DD, wo + W, bo + i * DD, c0);
        attn_k<<<BB, blk, 0, stream>>>(qbuf, wk + W, ctx, mbuf);
        gemm_k<false, true><<<dim3(DD / BN, BB / BM), blk, 0, stream>>>(
            mbuf, Wf, c0, x, x, BB, DD, HH * DD);
        ln_k<<<BB, blk, 0, stream>>>(x, ln2_s + i * DD, ln2_b + i * DD, hln);
        gemm_k<true, false><<<dim3(DFF / BN, BB / BM), blk, 0, stream>>>(
            hln, fw1 + (size_t)i * DD * DFF, fb1 + i * DFF, nullptr, ffh, BB, DFF, DD);
        gemm_k<false, true><<<dim3(DD / BN, BB / BM), blk, 0, stream>>>(
            ffh, fw2 + (size_t)i * DFF * DD, fb2 + i * DD, x, x, BB, DD, DFF);
    }

    // ---- head ----
    gemm_k<false, false><<<dim3(1, BB / BM), blk, 0, stream>>>(
        x, head_w, head_b, nullptr, out, BB, NCLS, DD);
}

// Round 7
// 1766.073 us; speedup vs baseline: 4.4494x; 1.3588x over previous
//
#include <hip/hip_runtime.h>
#include <hip/hip_bf16.h>
#include <math.h>

// ---------------------------------------------------------------------------
// Dims (fixed by the reference)
// ---------------------------------------------------------------------------
#define BB    1024      // batch
#define NCAND 100000    // candidates
#define DD    256       // d_main
#define CC    96        // context size
#define HH    8         // heads
#define DH    32        // head dim
#define NBLK  2
#define DENC  512
#define DFF   1024
#define NNUM  64
#define NCLS  10
#define CHQ   256       // query chunk for sims buffer

// top-k select: fixed-point buckets over sims in [-1,1]
#define NBUCK  4096
#define BSCALE 2048.0f
#define TIECAP 2048
#define NSEG   8
#define SEG4   3125     // float4 per segment = NCAND/4/NSEG
#define MARGIN 20       // bucket margin covering worst-case bf16 sims error

typedef __attribute__((ext_vector_type(8))) short s16x8;
typedef __attribute__((ext_vector_type(4))) float f32x4;

// ---------------------------------------------------------------------------
// fp32 tiled GEMM with register-prefetch pipeline and optional split-K.
// C[M,N] = act(A[M,K] @ B + bias) [+ res]   (B is K x N row-major)
// SPLIT: grid.z = K/klen; each z writes a partial [M,N] slab to C (no epilogue);
// red_k then sums slabs + bias/relu/res. M%64==0, K%16==0, klen%16==0.
// ---------------------------------------------------------------------------
#define BM 64
#define BN 64
#define BK 16

template <bool RELU, bool RES, bool SPLIT>
__global__ __launch_bounds__(256) void gemm2_k(const float* __restrict__ A,
                                               const float* __restrict__ B,
                                               const float* __restrict__ bias,
                                               const float* __restrict__ res,
                                               float* __restrict__ C,
                                               int M, int N, int K, int klen) {
    __shared__ __align__(16) float As[BK][BM + 4];
    __shared__ __align__(16) float Bs[BK][BN + 4];
    const int tid = threadIdx.x;
    const int bm = blockIdx.y * BM;
    const int bn = blockIdx.x * BN;
    const int kz = SPLIT ? blockIdx.z : 0;
    const int kbeg = kz * klen;
    const int nT = (SPLIT ? klen : K) / BK;
    const int tm = (tid >> 4) << 2;   // 0..60
    const int tn = (tid & 15) << 2;   // 0..60

    float acc[4][4] = {};
    float pa[4], pb[4];

    auto ldA = [&](int k0) {
#pragma unroll
        for (int l = 0; l < 4; ++l) {
            int lin = l * 256 + tid;
            int m = lin >> 4, k = lin & 15;
            pa[l] = A[(size_t)(bm + m) * K + k0 + k];
        }
    };
    auto ldB = [&](int k0) {
#pragma unroll
        for (int l = 0; l < 4; ++l) {
            int lin = l * 256 + tid;
            int k = lin >> 6, n = lin & 63;
            int gn = bn + n;
            pb[l] = (gn < N) ? B[(size_t)(k0 + k) * N + gn] : 0.f;
        }
    };

    ldA(kbeg);
    ldB(kbeg);
    for (int t = 0; t < nT; ++t) {
#pragma unroll
        for (int l = 0; l < 4; ++l) {
            int lin = l * 256 + tid;
            As[lin & 15][lin >> 4] = pa[l];
        }
#pragma unroll
        for (int l = 0; l < 4; ++l) {
            int lin = l * 256 + tid;
            Bs[lin >> 6][lin & 63] = pb[l];
        }
        __syncthreads();
        if (t + 1 < nT) {           // prefetch next tile while computing this one
            ldA(kbeg + (t + 1) * BK);
            ldB(kbeg + (t + 1) * BK);
        }
#pragma unroll
        for (int k = 0; k < BK; ++k) {
            float4 a4 = *(const float4*)&As[k][tm];
            float4 b4 = *(const float4*)&Bs[k][tn];
            float av[4] = {a4.x, a4.y, a4.z, a4.w};
            float bv[4] = {b4.x, b4.y, b4.z, b4.w};
#pragma unroll
            for (int i = 0; i < 4; ++i)
#pragma unroll
                for (int j = 0; j < 4; ++j) acc[i][j] += av[i] * bv[j];
        }
        __syncthreads();
    }

    if (SPLIT) {
        float* Cp = C + (size_t)kz * M * N;
#pragma unroll
        for (int i = 0; i < 4; ++i) {
            int r = bm + tm + i;
#pragma unroll
            for (int j = 0; j < 4; ++j) {
                int c = bn + tn + j;
                if (c < N) Cp[(size_t)r * N + c] = acc[i][j];
            }
        }
    } else {
#pragma unroll
        for (int i = 0; i < 4; ++i) {
            int r = bm + tm + i;
#pragma unroll
            for (int j = 0; j < 4; ++j) {
                int c = bn + tn + j;
                if (c < N) {
                    float v = acc[i][j];
                    if (bias) v += bias[c];
                    if (RELU) v = fmaxf(v, 0.f);
                    if (RES) v += res[(size_t)r * N + c];
                    C[(size_t)r * N + c] = v;
                }
            }
        }
    }
}

// split-K reduction epilogue (float4; requires N % 4 == 0)
template <bool RELU, bool RES>
__global__ __launch_bounds__(256) void red_k(const float* __restrict__ Cp,
                                             const float* __restrict__ bias,
                                             const float* __restrict__ res,
                                             float* __restrict__ C,
                                             int MN, int N, int KS) {
    int i = blockIdx.x * 256 + threadIdx.x;
    if (i >= (MN >> 2)) return;
    float4 s = ((const float4*)Cp)[i];
    for (int z = 1; z < KS; ++z) {
        float4 p = ((const float4*)(Cp + (size_t)z * MN))[i];
        s.x += p.x; s.y += p.y; s.z += p.z; s.w += p.w;
    }
    float4 b4 = ((const float4*)bias)[i % (N >> 2)];
    s.x += b4.x; s.y += b4.y; s.z += b4.z; s.w += b4.w;
    if (RELU) {
        s.x = fmaxf(s.x, 0.f); s.y = fmaxf(s.y, 0.f);
        s.z = fmaxf(s.z, 0.f); s.w = fmaxf(s.w, 0.f);
    }
    if (RES) {
        float4 r = ((const float4*)res)[i];
        s.x += r.x; s.y += r.y; s.z += r.z; s.w += r.w;
    }
    ((float4*)C)[i] = s;
}

// ---------------------------------------------------------------------------
// fp32 -> bf16 (round-to-nearest-even), 4 elements per thread
// ---------------------------------------------------------------------------
__device__ inline short f2bf(float f) {
    unsigned u = __float_as_uint(f);
    unsigned r = 0x7fffu + ((u >> 16) & 1u);
    return (short)((u + r) >> 16);
}

__global__ __launch_bounds__(256) void cvt_k(const float* __restrict__ in,
                                             short* __restrict__ out, int n4) {
    int i = blockIdx.x * 256 + threadIdx.x;
    if (i < n4) {
        float4 v = ((const float4*)in)[i];
        short4 o;
        o.x = f2bf(v.x); o.y = f2bf(v.y); o.z = f2bf(v.z); o.w = f2bf(v.w);
        ((short4*)out)[i] = o;
    }
}

// ---------------------------------------------------------------------------
// Sims GEMM on matrix cores (bf16 in, fp32 out), per-wave 64x64 tile, no LDS.
// ---------------------------------------------------------------------------
__global__ __launch_bounds__(256) void simsmm_k(const short* __restrict__ A,
                                                const short* __restrict__ B,
                                                float* __restrict__ C) {
    const int lane = threadIdx.x & 63;
    const int wid  = threadIdx.x >> 6;
    const int m0 = blockIdx.y * 64;
    const int n0 = blockIdx.x * 256 + wid * 64;
    const int lg = lane >> 4;          // 0..3
    const int lr = lane & 15;

    f32x4 acc[4][4];
#pragma unroll
    for (int i = 0; i < 4; ++i)
#pragma unroll
        for (int j = 0; j < 4; ++j) acc[i][j] = (f32x4){0.f, 0.f, 0.f, 0.f};

    for (int k0 = 0; k0 < DD; k0 += 32) {
        const int kb = k0 + lg * 8;
        s16x8 a[4], b[4];
#pragma unroll
        for (int i = 0; i < 4; ++i)
            a[i] = *(const s16x8*)(A + (size_t)(m0 + 16 * i + lr) * DD + kb);
#pragma unroll
        for (int j = 0; j < 4; ++j) {
            int rb = n0 + 16 * j + lr;
            rb = rb < NCAND ? rb : 0;
            b[j] = *(const s16x8*)(B + (size_t)rb * DD + kb);
        }
#pragma unroll
        for (int i = 0; i < 4; ++i)
#pragma unroll
            for (int j = 0; j < 4; ++j)
                acc[i][j] = __builtin_amdgcn_mfma_f32_16x16x32_bf16(a[i], b[j], acc[i][j], 0, 0, 0);
    }

#pragma unroll
    for (int i = 0; i < 4; ++i) {
        const int row = m0 + 16 * i + lg * 4;
#pragma unroll
        for (int j = 0; j < 4; ++j) {
            const int col = n0 + 16 * j + lr;
            if (col < NCAND) {
#pragma unroll
                for (int r = 0; r < 4; ++r)
                    C[(size_t)(row + r) * NCAND + col] = acc[i][j][r];
            }
        }
    }
}

// ---------------------------------------------------------------------------
// LayerNorm over D=256 (one block per row)
// ---------------------------------------------------------------------------
__global__ __launch_bounds__(256) void ln_k(const float* __restrict__ x,
                                            const float* __restrict__ s,
                                            const float* __restrict__ b,
                                            float* __restrict__ o) {
    __shared__ float red[256];
    const int row = blockIdx.x, tid = threadIdx.x;
    float v = x[(size_t)row * DD + tid];
    red[tid] = v;
    __syncthreads();
    for (int st = 128; st > 0; st >>= 1) {
        if (tid < st) red[tid] += red[tid + st];
        __syncthreads();
    }
    float mean = red[0] * (1.f / DD);
    __syncthreads();
    float d = v - mean;
    red[tid] = d * d;
    __syncthreads();
    for (int st = 128; st > 0; st >>= 1) {
        if (tid < st) red[tid] += red[tid + st];
        __syncthreads();
    }
    float var = red[0] * (1.f / DD);
    o[(size_t)row * DD + tid] = d / sqrtf(var + 1e-5f) * s[tid] + b[tid];
}

// ---------------------------------------------------------------------------
// Row L2-normalize (D=256)
// ---------------------------------------------------------------------------
__global__ __launch_bounds__(256) void l2norm_k(const float* __restrict__ in,
                                                float* __restrict__ out) {
    __shared__ float red[256];
    const int row = blockIdx.x, tid = threadIdx.x;
    float v = in[(size_t)row * DD + tid];
    red[tid] = v * v;
    __syncthreads();
    for (int st = 128; st > 0; st >>= 1) {
        if (tid < st) red[tid] += red[tid + st];
        __syncthreads();
    }
    float inv = 1.f / sqrtf(red[0]);
    out[(size_t)row * DD + tid] = v * inv;
}

// ---------------------------------------------------------------------------
// Top-96 select over approx sims (bucketed), exact-verified at the boundary.
// ---------------------------------------------------------------------------
__device__ inline int bucket_of(float s) {
    int b = (int)((s + 1.0f) * BSCALE);
    return b < 0 ? 0 : (b > NBUCK - 1 ? NBUCK - 1 : b);
}

// grid (NSEG, CHQ): per-block LDS histogram of a 12.5K-element segment
__global__ __launch_bounds__(256) void histl_k(const float* __restrict__ sims,
                                               unsigned* __restrict__ ghist) {
    __shared__ unsigned lh[NBUCK];
    const int q = blockIdx.y, tid = threadIdx.x;
    for (int i = tid; i < NBUCK; i += 256) lh[i] = 0;
    __syncthreads();
    const float4* r4 = (const float4*)(sims + (size_t)q * NCAND) + blockIdx.x * SEG4;
    for (int t = tid; t < SEG4; t += 256) {
        float4 v = r4[t];
        atomicAdd(&lh[bucket_of(v.x)], 1u);
        atomicAdd(&lh[bucket_of(v.y)], 1u);
        atomicAdd(&lh[bucket_of(v.z)], 1u);
        atomicAdd(&lh[bucket_of(v.w)], 1u);
    }
    __syncthreads();
    unsigned* h = ghist + (size_t)q * NBUCK;
    for (int i = tid; i < NBUCK; i += 256) {
        unsigned c = lh[i];
        if (c) atomicAdd(&h[i], c);
    }
}

// one block per query: find boundary bucket B1 (cum from top reaches >= 96)
__global__ __launch_bounds__(256) void thr_k(const unsigned* __restrict__ ghist,
                                             int* __restrict__ B1v,
                                             unsigned* __restrict__ cnt_def,
                                             unsigned* __restrict__ cnt_tie) {
    __shared__ unsigned part[256];
    const int q = blockIdx.x, tid = threadIdx.x;
    const unsigned* h = ghist + (size_t)q * NBUCK;
    unsigned s = 0;
#pragma unroll
    for (int i = 0; i < 16; ++i) s += h[tid * 16 + i];
    part[tid] = s;
    __syncthreads();
    if (tid == 0) {
        unsigned cum = 0;
        int seg = 0;
        for (int t = 255; t >= 0; --t) {
            if (cum + part[t] >= CC) { seg = t; break; }
            cum += part[t];
        }
        int b1 = seg * 16;
        for (int b = seg * 16 + 15; b >= seg * 16; --b) {
            if (cum + h[b] >= CC) { b1 = b; break; }
            cum += h[b];
        }
        B1v[q] = b1;
        cnt_def[q] = 0;
        cnt_tie[q] = 0;
    }
}

// grid (25, CHQ): emit definite winners and boundary ties
__global__ __launch_bounds__(256) void compact_k(const float* __restrict__ sims,
                                                 const int* __restrict__ B1v,
                                                 unsigned* __restrict__ cnt_def,
                                                 unsigned* __restrict__ cnt_tie,
                                                 float* __restrict__ tieval,
                                                 int* __restrict__ tieidx,
                                                 int* __restrict__ idxout, int qo) {
    const int q = blockIdx.y, tid = threadIdx.x;
    const float4* r4 = (const float4*)(sims + (size_t)q * NCAND);
    const int b1 = B1v[q];
    int* myout = idxout + (size_t)(qo + q) * CC;
    float* tv = tieval + (size_t)q * TIECAP;
    int* tix = tieidx + (size_t)q * TIECAP;
    const int base4 = blockIdx.x * 1000;
    for (int t = tid; t < 1000; t += 256) {
        float4 v = r4[base4 + t];
        float vv[4] = {v.x, v.y, v.z, v.w};
        int j = (base4 + t) * 4;
#pragma unroll
        for (int u = 0; u < 4; ++u) {
            int b = bucket_of(vv[u]);
            if (b > b1 + MARGIN) {
                unsigned p = atomicAdd(&cnt_def[q], 1u);
                myout[p] = j + u;
            } else if (b >= b1 - MARGIN) {
                unsigned p = atomicAdd(&cnt_tie[q], 1u);
                if (p < TIECAP) { tv[p] = vv[u]; tix[p] = j + u; }
            }
        }
    }
}

// one block per query: exact fp32 re-dot of ties, then exact selection
__global__ __launch_bounds__(256) void final_k(const float* __restrict__ xq,
                                               const float* __restrict__ ck,
                                               const unsigned* __restrict__ cnt_def,
                                               const unsigned* __restrict__ cnt_tie,
                                               float* __restrict__ tieval,
                                               const int* __restrict__ tieidx,
                                               int* __restrict__ idxout, int qo) {
    __shared__ float xs[DD];
    __shared__ float rv[256];
    __shared__ int rj[256];
    const int q = blockIdx.x, tid = threadIdx.x;
    const int lane = tid & 63, wav = tid >> 6;
    xs[tid] = xq[(size_t)(qo + q) * DD + tid];
    __syncthreads();
    const int base = (int)cnt_def[q];
    const int rem = CC - base;
    unsigned ct = cnt_tie[q];
    const int nt = (int)(ct < (unsigned)TIECAP ? ct : (unsigned)TIECAP);
    float* tv = tieval + (size_t)q * TIECAP;
    const int* tix = tieidx + (size_t)q * TIECAP;
    int* myout = idxout + (size_t)(qo + q) * CC;

    for (int t = wav; t < nt; t += 4) {
        const float* row = ck + (size_t)tix[t] * DD;
        float s = 0.f;
#pragma unroll
        for (int e = 0; e < 4; ++e) s += row[lane + 64 * e] * xs[lane + 64 * e];
        for (int off = 32; off > 0; off >>= 1) s += __shfl_down(s, off);
        if (lane == 0) tv[t] = s;
    }
    __syncthreads();

    for (int r = 0; r < rem; ++r) {
        float bvv = -1e30f;
        int bj = -1;
        for (int t = tid; t < nt; t += 256)
            if (tv[t] > bvv) { bvv = tv[t]; bj = t; }
        rv[tid] = bvv;
        rj[tid] = bj;
        __syncthreads();
        for (int st = 128; st > 0; st >>= 1) {
            if (tid < st && rv[tid + st] > rv[tid]) { rv[tid] = rv[tid + st]; rj[tid] = rj[tid + st]; }
            __syncthreads();
        }
        if (tid == 0) {
            myout[base + r] = tix[rj[0]];
            tv[rj[0]] = -1e30f;
        }
        __syncthreads();
    }
}

// ---------------------------------------------------------------------------
// ctx[b,c,:] = candidate_k[idx[b,c],:] + label_emb[candidate_y[idx[b,c]],:]
// ---------------------------------------------------------------------------
__global__ __launch_bounds__(256) void ctx_k(const int* __restrict__ idx,
                                             const float* __restrict__ ck,
                                             const int* __restrict__ cy,
                                             const float* __restrict__ le,
                                             float* __restrict__ ctx) {
    const int row = blockIdx.x, tid = threadIdx.x;
    const int i = idx[row];
    const int y = cy[i];
    ctx[(size_t)row * DD + tid] = ck[(size_t)i * DD + tid] + le[(size_t)y * DD + tid];
}

// ---------------------------------------------------------------------------
// Wf[(h*256+e), f] = sum_d wv[e, h*32+d] * wo[h*32+d, f]
// ---------------------------------------------------------------------------
__global__ __launch_bounds__(256) void wfuse_k(const float* __restrict__ wv,
                                               const float* __restrict__ wo,
                                               float* __restrict__ Wf) {
    const int r = blockIdx.x;          // h*256 + e
    const int h = r >> 8, e = r & 255;
    const int f = threadIdx.x;
    float acc = 0.f;
#pragma unroll
    for (int d = 0; d < DH; ++d)
        acc += wv[(size_t)e * DD + h * DH + d] * wo[(size_t)(h * DH + d) * DD + f];
    Wf[(size_t)r * DD + f] = acc;
}

// c0[f] = bv @ wo + bo
__global__ __launch_bounds__(256) void c0_k(const float* __restrict__ bv,
                                            const float* __restrict__ wo,
                                            const float* __restrict__ bo,
                                            float* __restrict__ c0) {
    const int f = threadIdx.x;
    float acc = bo[f];
    for (int r = 0; r < DD; ++r) acc += bv[r] * wo[(size_t)r * DD + f];
    c0[f] = acc;
}

// ---------------------------------------------------------------------------
// Fused attention (per batch row b)
// ---------------------------------------------------------------------------
__global__ __launch_bounds__(256) void attn_k(const float* __restrict__ qb,
                                              const float* __restrict__ wk,
                                              const float* __restrict__ ctx,
                                              float* __restrict__ mout) {
    __shared__ float qs[DD];
    __shared__ float ts[HH * DD];
    __shared__ float ss[HH * CC];
    const int b = blockIdx.x, tid = threadIdx.x;
    qs[tid] = qb[(size_t)b * DD + tid];
    __syncthreads();

    for (int idx = tid; idx < HH * DD; idx += 256) {
        const int h = idx >> 8, e = idx & 255;
        float acc = 0.f;
#pragma unroll
        for (int d = 0; d < DH; ++d) acc += qs[h * DH + d] * wk[(size_t)e * DD + h * DH + d];
        ts[idx] = acc;
    }
    __syncthreads();

    const float scale = 0.17677669529663687f;  // 1/sqrt(32)
    const float* cb = ctx + (size_t)b * CC * DD;
    for (int o = tid; o < HH * CC; o += 256) {
        const int c = o >> 3, h = o & 7;
        const float* cr = cb + (size_t)c * DD;
        const float* th = ts + h * DD;
        float acc = 0.f;
        for (int e = 0; e < DD; ++e) acc += cr[e] * th[e];
        ss[h * CC + c] = acc * scale;
    }
    __syncthreads();

    if (tid < HH) {
        const int h = tid;
        float mx = -1e30f;
        for (int c = 0; c < CC; ++c) mx = fmaxf(mx, ss[h * CC + c]);
        float sum = 0.f;
        for (int c = 0; c < CC; ++c) {
            float e = expf(ss[h * CC + c] - mx);
            ss[h * CC + c] = e;
            sum += e;
        }
        float inv = 1.f / sum;
        for (int c = 0; c < CC; ++c) ss[h * CC + c] *= inv;
    }
    __syncthreads();

    float acc[HH] = {};
    for (int c = 0; c < CC; ++c) {
        float v = cb[(size_t)c * DD + tid];
#pragma unroll
        for (int h = 0; h < HH; ++h) acc[h] += ss[h * CC + c] * v;
    }
#pragma unroll
    for (int h = 0; h < HH; ++h) mout[(size_t)b * (HH * DD) + h * DD + tid] = acc[h];
}

// ---------------------------------------------------------------------------
// Host launcher
// ---------------------------------------------------------------------------
extern "C" void kernel_launch(void* const* d_in, const int* in_sizes, int n_in,
                              void* d_out, int out_size, void* d_ws, size_t ws_size,
                              hipStream_t stream) {
    (void)in_sizes; (void)n_in; (void)out_size; (void)ws_size;
    const float* x_num  = (const float*)d_in[0];
    const float* cand_k = (const float*)d_in[1];
    const int*   cand_y = (const int*)d_in[2];
    const float* enc_w0 = (const float*)d_in[3];
    const float* enc_b0 = (const float*)d_in[4];
    const float* enc_ln_s = (const float*)d_in[5];
    const float* enc_ln_b = (const float*)d_in[6];
    const float* enc_w1 = (const float*)d_in[7];
    const float* enc_b1 = (const float*)d_in[8];
    const float* enc_w2 = (const float*)d_in[9];
    const float* enc_b2 = (const float*)d_in[10];
    const float* label_emb = (const float*)d_in[11];
    const float* ln1_s = (const float*)d_in[12];
    const float* ln1_b = (const float*)d_in[13];
    const float* wq = (const float*)d_in[14];
    const float* bq = (const float*)d_in[15];
    const float* wk = (const float*)d_in[16];
    // d_in[17] = bk : constant shift per (b,h) inside softmax -> drops out
    const float* wv = (const float*)d_in[18];
    const float* bv = (const float*)d_in[19];
    const float* wo = (const float*)d_in[20];
    const float* bo = (const float*)d_in[21];
    const float* ln2_s = (const float*)d_in[22];
    const float* ln2_b = (const float*)d_in[23];
    const float* fw1 = (const float*)d_in[24];
    const float* fb1 = (const float*)d_in[25];
    const float* fw2 = (const float*)d_in[26];
    const float* fb2 = (const float*)d_in[27];
    const float* head_w = (const float*)d_in[28];
    const float* head_b = (const float*)d_in[29];
    float* out = (float*)d_out;

    char* ws = (char*)d_ws;
    size_t off = 0;
    auto alloc = [&](size_t bytes) -> void* {
        void* p = ws + off;
        off += (bytes + 255) & ~(size_t)255;
        return p;
    };
    float* big  = (float*)alloc((size_t)CHQ * NCAND * 4);   // sims chunk, reused as ctx
    float* h0   = (float*)alloc((size_t)BB * DD * 4);
    float* h1   = (float*)alloc((size_t)BB * DENC * 4);
    float* hln  = (float*)alloc((size_t)BB * DD * 4);
    float* x    = (float*)alloc((size_t)BB * DD * 4);       // query, then residual stream
    float* qbuf = (float*)alloc((size_t)BB * DD * 4);
    int*   idxb = (int*)alloc((size_t)BB * CC * 4);
    float* mbuf = (float*)alloc((size_t)BB * HH * DD * 4);
    float* Wf   = (float*)alloc((size_t)HH * DD * DD * 4);
    float* c0   = (float*)alloc(DD * 4);
    float* ffh  = (float*)alloc((size_t)BB * DFF * 4);
    float* cpart = (float*)alloc((size_t)8 * BB * DD * 4);  // split-K partials (KS<=8)
    unsigned* ghist  = (unsigned*)alloc((size_t)CHQ * NBUCK * 4);
    int*      B1v    = (int*)alloc((size_t)CHQ * 4);
    unsigned* cntd   = (unsigned*)alloc((size_t)CHQ * 4);
    unsigned* cntt   = (unsigned*)alloc((size_t)CHQ * 4);
    float*    tieval = (float*)alloc((size_t)CHQ * TIECAP * 4);
    int*      tieidx = (int*)alloc((size_t)CHQ * TIECAP * 4);
    short*    ckbf   = (short*)alloc((size_t)NCAND * DD * 2);
    short*    xbf    = (short*)alloc((size_t)BB * DD * 2);
    float* ctx  = big;

    dim3 blk(256);
    const int RB = (BB * DD / 4 + 255) / 256;   // red_k grid for M*N = BB*DD

    // ---- candidate_k -> bf16 (once) ----
    cvt_k<<<(NCAND * DD / 4 + 255) / 256, blk, 0, stream>>>(cand_k, ckbf, NCAND * DD / 4);

    // ---- encoder ----
    gemm2_k<false, false, false><<<dim3(DD / BN, BB / BM), blk, 0, stream>>>(
        x_num, enc_w0, enc_b0, nullptr, h0, BB, DD, NNUM, 0);
    for (int i = 0; i < NBLK; ++i) {
        ln_k<<<BB, blk, 0, stream>>>(h0, enc_ln_s + i * DD, enc_ln_b + i * DD, hln);
        gemm2_k<true, false, false><<<dim3(DENC / BN, BB / BM), blk, 0, stream>>>(
            hln, enc_w1 + (size_t)i * DD * DENC, enc_b1 + i * DENC, nullptr, h1, BB, DENC, DD, 0);
        gemm2_k<false, false, true><<<dim3(DD / BN, BB / BM, DENC / 256), blk, 0, stream>>>(
            h1, enc_w2 + (size_t)i * DENC * DD, nullptr, nullptr, cpart, BB, DD, DENC, 256);
        red_k<false, false><<<RB, blk, 0, stream>>>(cpart, enc_b2 + i * DD, nullptr, h0,
                                                    BB * DD, DD, DENC / 256);
    }
    l2norm_k<<<BB, blk, 0, stream>>>(h0, x);  // x = query (fp32, exact)
    cvt_k<<<(BB * DD / 4 + 255) / 256, blk, 0, stream>>>(x, xbf, BB * DD / 4);

    // ---- retrieval: bf16-MFMA sims + margin-verified exact top-96 ----
    for (int ci = 0; ci < BB / CHQ; ++ci) {
        const int qo = ci * CHQ;
        hipMemsetAsync(ghist, 0, (size_t)CHQ * NBUCK * 4, stream);
        simsmm_k<<<dim3((NCAND + 255) / 256, CHQ / 64), blk, 0, stream>>>(
            xbf + (size_t)qo * DD, ckbf, big);
        histl_k<<<dim3(NSEG, CHQ), blk, 0, stream>>>(big, ghist);
        thr_k<<<CHQ, blk, 0, stream>>>(ghist, B1v, cntd, cntt);
        compact_k<<<dim3(25, CHQ), blk, 0, stream>>>(big, B1v, cntd, cntt, tieval, tieidx, idxb, qo);
        final_k<<<CHQ, blk, 0, stream>>>(x, cand_k, cntd, cntt, tieval, tieidx, idxb, qo);
    }
    ctx_k<<<BB * CC, blk, 0, stream>>>(idxb, cand_k, cand_y, label_emb, ctx);

    // ---- transformer mixer (associativity-restructured attention) ----
    for (int i = 0; i < NBLK; ++i) {
        const size_t W = (size_t)i * DD * DD;
        ln_k<<<BB, blk, 0, stream>>>(x, ln1_s + i * DD, ln1_b + i * DD, hln);
        gemm2_k<false, false, false><<<dim3(DD / BN, BB / BM), blk, 0, stream>>>(
            hln, wq + W, bq + i * DD, nullptr, qbuf, BB, DD, DD, 0);
        wfuse_k<<<HH * DD, blk, 0, stream>>>(wv + W, wo + W, Wf);
        c0_k<<<1, blk, 0, stream>>>(bv + i * DD, wo + W, bo + i * DD, c0);
        attn_k<<<BB, blk, 0, stream>>>(qbuf, wk + W, ctx, mbuf);
        // x += mbuf @ Wf + c0   (split-K over K = 2048)
        gemm2_k<false, false, true><<<dim3(DD / BN, BB / BM, (HH * DD) / 256), blk, 0, stream>>>(
            mbuf, Wf, nullptr, nullptr, cpart, BB, DD, HH * DD, 256);
        red_k<false, true><<<RB, blk, 0, stream>>>(cpart, c0, x, x, BB * DD, DD, (HH * DD) / 256);
        ln_k<<<BB, blk, 0, stream>>>(x, ln2_s + i * DD, ln2_b + i * DD, hln);
        gemm2_k<true, false, false><<<dim3(DFF / BN, BB / BM), blk, 0, stream>>>(
            hln, fw1 + (size_t)i * DD * DFF, fb1 + i * DFF, nullptr, ffh, BB, DFF, DD, 0);
        // x += ffh @ fw2 + fb2   (split-K over K = 1024)
        gemm2_k<false, false, true><<<dim3(DD / BN, BB / BM, DFF / 256), blk, 0, stream>>>(
            ffh, fw2 + (size_t)i * DFF * DD, nullptr, nullptr, cpart, BB, DD, DFF, 256);
        red_k<false, true><<<RB, blk, 0, stream>>>(cpart, fb2 + i * DD, x, x, BB * DD, DD, DFF / 256);
    }

    // ---- head ----
    gemm2_k<false, false, false><<<dim3(1, BB / BM), blk, 0, stream>>>(
        x, head_w, head_b, nullptr, out, BB, NCLS, DD, 0);
}